// Round 8
// baseline (1158.397 us; speedup 1.0000x reference)
//
#include <hip/hip_runtime.h>
#include <hip/hip_bf16.h>
#include <math.h>

#define L_ 4
#define B_ 64
#define N_ 511
#define D_ 256
#define H_ 8
#define DFF_ 512
#define S_ 512
#define HD_ 32
#define BW_ 7
#define BS_ (B_*S_)   // 32768 rows

typedef __attribute__((ext_vector_type(8))) short short8;   // 8 x bf16 bits
typedef __attribute__((ext_vector_type(4))) short short4v;  // 4 x bf16 bits
typedef __attribute__((ext_vector_type(4))) float f32x4;

#define L2E 1.44269504088896340f
#define QSCL (0.17677669529663687f * 1.44269504088896340f)   // rscale * log2(e)

#if defined(__HIP_DEVICE_COMPILE__) && __has_builtin(__builtin_amdgcn_exp2f)
#define EXP2(x) __builtin_amdgcn_exp2f(x)
#else
#define EXP2(x) exp2f(x)
#endif

__device__ inline ushort f2b(float f) {
    unsigned u = __float_as_uint(f);
    unsigned r = (u + 0x7fffu + ((u >> 16) & 1u)) >> 16;   // RNE
    return (ushort)r;
}

// packed f32x2 -> bf16x2 in one uint (low = a); HW op on gfx950, SW fallback
#if defined(__HIP_DEVICE_COMPILE__) && __has_builtin(__builtin_amdgcn_cvt_pk_bf16_f32)
typedef __attribute__((ext_vector_type(2))) __bf16 bf16x2_t;
__device__ inline uint pk_bf16(float a, float b) {
    bf16x2_t r = __builtin_amdgcn_cvt_pk_bf16_f32(a, b);
    return *(uint*)&r;
}
#else
__device__ inline uint pk_bf16(float a, float b) {
    return (uint)f2b(a) | ((uint)f2b(b) << 16);
}
#endif

// 4-way ADDITIVE bias lookup (log2 domain) returning f32x4 in MFMA C-layout.
// bf16 table via raw v_perm_b32: selectors are BYTE-packed (b = low source,
// idx 0-3; a = high, 4-7).
__device__ inline f32x4 bsel4v(uint E, uint tlo, uint thi) {
    f32x4 r;
#if defined(__HIP_DEVICE_COMPILE__) && __has_builtin(__builtin_amdgcn_perm)
    uint E2  = E + E;                 // per-byte 2e (e<=3: no carry)
    uint E2b = E2 | 0x01010101u;      // per-byte 2e+1
    uint s01 = __builtin_amdgcn_perm(E2b, E2, 0x05010400u);  // [2e0,2e0+1,2e1,2e1+1]
    uint s23 = __builtin_amdgcn_perm(E2b, E2, 0x07030602u);  // [2e2,2e2+1,2e3,2e3+1]
    uint p01 = __builtin_amdgcn_perm(thi, tlo, s01);         // bf16 bl[e0] | bl[e1]<<16
    uint p23 = __builtin_amdgcn_perm(thi, tlo, s23);
    r[0] = __uint_as_float(p01 << 16);
    r[1] = __uint_as_float(p01 & 0xFFFF0000u);
    r[2] = __uint_as_float(p23 << 16);
    r[3] = __uint_as_float(p23 & 0xFFFF0000u);
#else
    #pragma unroll
    for (int i = 0; i < 4; i++) {
        unsigned char e = (unsigned char)((E >> (8 * i)) & 0xff);
        uint bb = e == 0 ? (tlo & 0xFFFFu) : (e == 1 ? (tlo >> 16) :
                  (e == 2 ? (thi & 0xFFFFu) : 0u));
        r[i] = __uint_as_float(bb << 16);
    }
#endif
    return r;
}

// async global->LDS 16B; fallback if builtin missing (host pass)
__device__ inline void gload16(const void* g, void* l) {
#if __has_builtin(__builtin_amdgcn_global_load_lds)
    __builtin_amdgcn_global_load_lds(
        (const __attribute__((address_space(1))) void*)g,
        (__attribute__((address_space(3))) void*)l, 16, 0, 0);
#else
    *(short8*)l = *(const short8*)g;
#endif
}

// ---------------------------------------------------------------------------
// Fused: x = [game_token, patch_emb[cell_states]] (fp32 out) AND h = LN1(x)
// (bf16 out) in one pass. Block = 4 waves, one row per wave.
__global__ __launch_bounds__(256) void build_ln(const int* __restrict__ cs,
                                                const float* __restrict__ patch,
                                                const float* __restrict__ game,
                                                const float* __restrict__ gw,
                                                const float* __restrict__ bw,
                                                float* __restrict__ x,
                                                ushort* __restrict__ h)
{
    int t = threadIdx.x;
    int lane = t & 63;
    int wv = t >> 6;
    int row = blockIdx.x * 4 + wv;            // b*S + s
    int s = row & (S_ - 1);
    float4 v;
    if (s == 0) {
        v = ((const float4*)game)[lane];
    } else {
        int b = row >> 9;
        int cell = cs[b * N_ + s - 1];
        v = ((const float4*)(patch + cell * D_))[lane];
    }
    ((float4*)x)[(size_t)row * 64 + lane] = v;

    float sm = v.x + v.y + v.z + v.w;
    #pragma unroll
    for (int o = 32; o >= 1; o >>= 1) sm += __shfl_xor(sm, o);
    float mean = sm * (1.f / 256.f);
    float dx = v.x - mean, dy = v.y - mean, dz = v.z - mean, dw = v.w - mean;
    float s2 = dx * dx + dy * dy + dz * dz + dw * dw;
    #pragma unroll
    for (int o = 32; o >= 1; o >>= 1) s2 += __shfl_xor(s2, o);
    float rstd = rsqrtf(s2 * (1.f / 256.f) + 1e-5f);
    float4 g  = *(const float4*)(gw + lane * 4);
    float4 bb = *(const float4*)(bw + lane * 4);
    ushort4 o4;
    o4.x = f2b(dx * rstd * g.x + bb.x);
    o4.y = f2b(dy * rstd * g.y + bb.y);
    o4.z = f2b(dz * rstd * g.z + bb.z);
    o4.w = f2b(dw * rstd * g.w + bb.w);
    *(ushort4*)(h + (size_t)row * D_ + lane * 4) = o4;
}

// ---------------------------------------------------------------------------
// et8[b][q][k] = (q>0 && k>0) ? et[b][q-1][k-1] : 3   (3 -> bias 0)
__global__ __launch_bounds__(256) void build_et8(const int* __restrict__ et,
                                                 unsigned char* __restrict__ et8)
{
    long idx = (long)blockIdx.x * 256 + threadIdx.x;  // over B*S*S
    int k = (int)(idx & (S_ - 1));
    long rem = idx >> 9;                              // b*S + q
    int q = (int)(rem & (S_ - 1));
    int b = (int)(rem >> 9);
    unsigned char v = 3;
    if (q > 0 && k > 0) {
        v = (unsigned char)et[((long)b * N_ + (q - 1)) * N_ + (k - 1)];
    }
    et8[idx] = v;
}

// ---------------------------------------------------------------------------
// All weight conversions in ONE kernel.
__global__ __launch_bounds__(256) void convert_all(const float* __restrict__ in_w,
                                                   const float* __restrict__ out_w,
                                                   const float* __restrict__ ff1_w,
                                                   const float* __restrict__ ff2_w,
                                                   ushort* __restrict__ inwb,
                                                   ushort* __restrict__ outwb,
                                                   ushort* __restrict__ ff1wb,
                                                   ushort* __restrict__ ff2wb)
{
    int i = blockIdx.x * 256 + threadIdx.x;   // 0 .. 524287
    const float* src;
    ushort* dst;
    int j;
    float s = 1.f;
    if (i < 196608) {
        j = i; src = in_w; dst = inwb;
        int r = (j >> 6) % 768;               // 64 float4s per 256-col row
        if (r < 256) s = (float)QSCL;
    } else if (i < 262144) {
        j = i - 196608; src = out_w; dst = outwb;
    } else if (i < 393216) {
        j = i - 262144; src = ff1_w; dst = ff1wb;
    } else {
        j = i - 393216; src = ff2_w; dst = ff2wb;
    }
    float4 v = ((const float4*)src)[j];
    ushort4 o4;
    o4.x = f2b(v.x * s); o4.y = f2b(v.y * s); o4.z = f2b(v.z * s); o4.w = f2b(v.w * s);
    ((ushort4*)dst)[j] = o4;
}

// ---------------------------------------------------------------------------
// m97-style LDS GEMM, BK=64 via TWO [128][32] k-half planes (halves the
// barrier-drain count; split planes keep ds_reads conflict-free).
template<int K, int NT, bool RELU, bool QSC, bool QKV>
__global__ __launch_bounds__(256, 2) void gemm_lds(const ushort* __restrict__ A,
                                                   const ushort* __restrict__ W,
                                                   const float* __restrict__ bias,
                                                   ushort* __restrict__ Cout,
                                                   ushort* __restrict__ Kb,
                                                   ushort* __restrict__ Vt)
{
    __shared__ ushort As[2][4096];    // [khalf][128 rows x 32]
    __shared__ ushort Ws[2][4096];
    const int N = NT * 128;
    int t = threadIdx.x;
    int wave = t >> 6, lane = t & 63;
    int lr = lane & 15, quad = lane >> 4;
    int lk = quad * 8;
    int blk = blockIdx.x;                      // grid = NT*256
    int xcd = blk & 7, idx = blk >> 3;
    int m0 = (xcd * 32 + (idx & 31)) * 128;
    int n0 = (idx >> 5) * 128;
    int mh = (wave >> 1) * 64, nh = (wave & 1) * 64;

    const ushort* ga0 = A + (size_t)(m0 + (t >> 2)) * K + (t & 3) * 8;
    const ushort* ga1 = ga0 + (size_t)64 * K;
    const ushort* gw0 = W + (size_t)(n0 + (t >> 2)) * K + (t & 3) * 8;
    const ushort* gw1 = gw0 + (size_t)64 * K;
    int t8 = t * 8;

    f32x4 acc[4][4];
    f32x4 zz = {0.f, 0.f, 0.f, 0.f};
    #pragma unroll
    for (int i = 0; i < 4; i++)
        #pragma unroll
        for (int j = 0; j < 4; j++) acc[i][j] = zz;

    for (int k0 = 0; k0 < K; k0 += 64) {
        gload16(ga0 + k0,      &As[0][t8]);
        gload16(ga1 + k0,      &As[0][t8 + 2048]);
        gload16(ga0 + k0 + 32, &As[1][t8]);
        gload16(ga1 + k0 + 32, &As[1][t8 + 2048]);
        gload16(gw0 + k0,      &Ws[0][t8]);
        gload16(gw1 + k0,      &Ws[0][t8 + 2048]);
        gload16(gw0 + k0 + 32, &Ws[1][t8]);
        gload16(gw1 + k0 + 32, &Ws[1][t8 + 2048]);
        __syncthreads();
        short8 af[2][4], wf[2][4];
        #pragma unroll
        for (int kk = 0; kk < 2; kk++) {
            #pragma unroll
            for (int i = 0; i < 4; i++) af[kk][i] = *(const short8*)&As[kk][(mh + i * 16 + lr) * 32 + lk];
            #pragma unroll
            for (int j = 0; j < 4; j++) wf[kk][j] = *(const short8*)&Ws[kk][(nh + j * 16 + lr) * 32 + lk];
        }
        #pragma unroll
        for (int kk = 0; kk < 2; kk++)
            #pragma unroll
            for (int i = 0; i < 4; i++)
                #pragma unroll
                for (int j = 0; j < 4; j++)
                    acc[i][j] = __builtin_amdgcn_mfma_f32_16x16x32_bf16(af[kk][i], wf[kk][j], acc[i][j], 0, 0, 0);
        __syncthreads();
    }

    #pragma unroll
    for (int nt = 0; nt < 4; nt++) {
        int colbase = n0 + nh + nt * 16;       // 16-aligned; regions 256-aligned
        int col = colbase + lr;
        float bv = bias[col];
        if (QSC && colbase < 256) bv *= (float)QSCL;
        int region = QKV ? (colbase >> 8) : 0; // wave-uniform
        #pragma unroll
        for (int mt = 0; mt < 4; mt++) {
            int rowb = m0 + mh + mt * 16 + quad * 4;
            if (!QKV || region == 0) {
                #pragma unroll
                for (int r = 0; r < 4; r++) {
                    size_t cidx = (size_t)(rowb + r) * N + col;
                    float v = acc[mt][nt][r] + bv;
                    if (RELU) v = fmaxf(v, 0.f);
                    Cout[cidx] = f2b(v);
                }
            } else if (region == 1) {          // K -> Kb[b,h,s,32]
                int hh = (col >> 5) & 7, d = col & 31;
                int bb = rowb >> 9, s = rowb & 511;
                size_t kbase = ((size_t)(bb * 8 + hh) * 512 + s) * 32 + d;
                #pragma unroll
                for (int r = 0; r < 4; r++)
                    Kb[kbase + (size_t)r * 32] = f2b(acc[mt][nt][r] + bv);
            } else {                           // V -> Vt[bh][s/16][d][16] tiled
                int hh = (col >> 5) & 7, d = col & 31;
                int bb = rowb >> 9, s = rowb & 511;
                ushort4 w;
                w.x = f2b(acc[mt][nt][0] + bv);
                w.y = f2b(acc[mt][nt][1] + bv);
                w.z = f2b(acc[mt][nt][2] + bv);
                w.w = f2b(acc[mt][nt][3] + bv);
                size_t vidx = (((size_t)(bb * 8 + hh) * 32 + (s >> 4)) * 32 + d) * 16 + (s & 15);
                *(ushort4*)&Vt[vidx] = w;
            }
        }
    }
}

// ---------------------------------------------------------------------------
// Fused residual GEMM + LayerNorm, BK=64 via two k-half planes.
// Block = 64 rows x 256 cols; grid 512, (256,2).
template<int K>
__global__ __launch_bounds__(256, 2) void gemm_ln(const ushort* __restrict__ A,
                                                  const ushort* __restrict__ W,
                                                  const float* __restrict__ bias,
                                                  float* __restrict__ X,
                                                  const float* __restrict__ lng,
                                                  const float* __restrict__ lnb,
                                                  ushort* __restrict__ Hout)
{
    __shared__ ushort As[2][2048];      //  8 KB  [khalf][64 x 32]
    __shared__ ushort Ws[2][8192];      // 32 KB  [khalf][256 x 32]
    __shared__ float lds_s[64][4];      //  1 KB
    __shared__ float lds_q[64][4];      //  1 KB
    int t = threadIdx.x;
    int wave = t >> 6, lane = t & 63;
    int lr = lane & 15, quad = lane >> 4;
    int lk = quad * 8;
    int blk = blockIdx.x;               // grid 512
    int xcd = blk & 7;
    int m0 = (xcd * 64 + (blk >> 3)) * 64;
    int nh = wave * 64;

    const ushort* ga = A + (size_t)(m0 + (t >> 2)) * K + (t & 3) * 8;
    const ushort* gw = W + (size_t)(t >> 2) * K + (t & 3) * 8;
    int t8 = t * 8;

    f32x4 acc[4][4];
    f32x4 zz = {0.f, 0.f, 0.f, 0.f};
    #pragma unroll
    for (int i = 0; i < 4; i++)
        #pragma unroll
        for (int j = 0; j < 4; j++) acc[i][j] = zz;

    for (int k0 = 0; k0 < K; k0 += 64) {
        gload16(ga + k0,      &As[0][t8]);
        gload16(ga + k0 + 32, &As[1][t8]);
        #pragma unroll
        for (int j = 0; j < 4; j++) {
            gload16(gw + (size_t)(j * 64) * K + k0,      &Ws[0][t8 + j * 2048]);
            gload16(gw + (size_t)(j * 64) * K + k0 + 32, &Ws[1][t8 + j * 2048]);
        }
        __syncthreads();
        short8 af[2][4], wf[2][4];
        #pragma unroll
        for (int kk = 0; kk < 2; kk++) {
            #pragma unroll
            for (int i = 0; i < 4; i++) af[kk][i] = *(const short8*)&As[kk][(i * 16 + lr) * 32 + lk];
            #pragma unroll
            for (int j = 0; j < 4; j++) wf[kk][j] = *(const short8*)&Ws[kk][(nh + j * 16 + lr) * 32 + lk];
        }
        #pragma unroll
        for (int kk = 0; kk < 2; kk++)
            #pragma unroll
            for (int i = 0; i < 4; i++)
                #pragma unroll
                for (int j = 0; j < 4; j++)
                    acc[i][j] = __builtin_amdgcn_mfma_f32_16x16x32_bf16(af[kk][i], wf[kk][j], acc[i][j], 0, 0, 0);
        __syncthreads();
    }

    // epilogue pass 1: v = acc + bias + X; store X; keep v in acc; row partials
    float gc[4], bc[4], bi[4];
    #pragma unroll
    for (int nt = 0; nt < 4; nt++) {
        int col = nh + nt * 16 + lr;
        gc[nt] = lng[col]; bc[nt] = lnb[col]; bi[nt] = bias[col];
    }
    float psum[16], psq[16];
    #pragma unroll
    for (int e = 0; e < 16; e++) { psum[e] = 0.f; psq[e] = 0.f; }
    #pragma unroll
    for (int nt = 0; nt < 4; nt++) {
        #pragma unroll
        for (int mt = 0; mt < 4; mt++) {
            #pragma unroll
            for (int r = 0; r < 4; r++) {
                int row = m0 + mt * 16 + quad * 4 + r;
                size_t idx = (size_t)row * D_ + nh + nt * 16 + lr;
                float v = acc[mt][nt][r] + bi[nt] + X[idx];
                X[idx] = v;
                acc[mt][nt][r] = v;
                psum[mt * 4 + r] += v;
                psq[mt * 4 + r]  += v * v;
            }
        }
    }
    // reduce over lr (16 lanes per quad hold disjoint cols of same rows)
    #pragma unroll
    for (int e = 0; e < 16; e++) {
        float s = psum[e], q = psq[e];
        s += __shfl_xor(s, 1); q += __shfl_xor(q, 1);
        s += __shfl_xor(s, 2); q += __shfl_xor(q, 2);
        s += __shfl_xor(s, 4); q += __shfl_xor(q, 4);
        s += __shfl_xor(s, 8); q += __shfl_xor(q, 8);
        psum[e] = s; psq[e] = q;
    }
    if (lr == 0) {
        #pragma unroll
        for (int mt = 0; mt < 4; mt++)
            #pragma unroll
            for (int r = 0; r < 4; r++) {
                int rl = mt * 16 + quad * 4 + r;
                lds_s[rl][wave] = psum[mt * 4 + r];
                lds_q[rl][wave] = psq[mt * 4 + r];
            }
    }
    __syncthreads();
    // epilogue pass 2: finalize stats, write h
    #pragma unroll
    for (int mt = 0; mt < 4; mt++) {
        #pragma unroll
        for (int r = 0; r < 4; r++) {
            int rl = mt * 16 + quad * 4 + r;
            f32x4 ss = *(const f32x4*)lds_s[rl];
            f32x4 qq = *(const f32x4*)lds_q[rl];
            float s = ss[0] + ss[1] + ss[2] + ss[3];
            float q = qq[0] + qq[1] + qq[2] + qq[3];
            float mean = s * (1.f / 256.f);
            float rstd = rsqrtf(q * (1.f / 256.f) - mean * mean + 1e-5f);
            int row = m0 + mt * 16 + quad * 4 + r;
            #pragma unroll
            for (int nt = 0; nt < 4; nt++) {
                size_t idx = (size_t)row * D_ + nh + nt * 16 + lr;
                float hv = (acc[mt][nt][r] - mean) * rstd * gc[nt] + bc[nt];
                Hout[idx] = f2b(hv);
            }
        }
    }
}

// ---------------------------------------------------------------------------
// Flash attention, barrier-free, R8: (256,4) -> (256,8).
// The R4-R7 structure allocates 52 VGPRs — it FITS the 64-VGPR budget that
// 8 waves/EU imposes (R2's spill was a different structure needing ~90).
// Barrier-free + 8 blocks/CU is the combination no prior round had:
// R1 = high occupancy + per-iter drains; R4-R7 = no drains + 35% occupancy.
__global__ __launch_bounds__(256, 8) void attn_mfma(const ushort* __restrict__ qkv,
                                                    const ushort* __restrict__ Kb,
                                                    const ushort* __restrict__ Vt,
                                                    const unsigned char* __restrict__ et8,
                                                    const float* __restrict__ eemb,
                                                    ushort* __restrict__ o)
{
    int t = threadIdx.x;
    int wave = t >> 6, lane = t & 63;
    int lr = lane & 15, quad = lane >> 4;
    int lk = quad * 8;
    int blk = blockIdx.x;                    // grid 2048
    int b = ((blk >> 8) << 3) | (blk & 7);   // same-b blocks -> same XCD
    int h = (blk >> 3) & 7;
    int qq = (blk >> 6) & 3;
    int bh = b * 8 + h;
    int q0 = qq * 128 + wave * 32;
    // additive bias table (log2 domain): exp2(s + b*L2E)
    float eb0 = eemb[h] * L2E, eb1 = eemb[8 + h] * L2E, eb2 = eemb[16 + h] * L2E;
    uint tlo = (uint)f2b(eb0) | ((uint)f2b(eb1) << 16);
    uint thi = (uint)f2b(eb2);               // high half = bf16 0.0 for e==3

    short8 qf[2];
    #pragma unroll
    for (int X = 0; X < 2; X++)
        qf[X] = *(const short8*)(qkv + ((size_t)(b * S_ + q0 + X * 16 + lr)) * 768 + h * 32 + lk);
    // permuted K pointer: A row m=lr holds K seq g(lr) = (lr>>2)*8 + (lr&3)
    int gl = ((lr >> 2) << 3) | (lr & 3);
    const ushort* Kp = Kb + ((size_t)(bh * S_) + gl) * 32 + lk;
    // V B-fragment (16x16x32): lane needs V[k0+quad*8+j][d=lr], j=0..7
    //  = Vt tile (k0>>4)+(quad>>1), d=lr, sl=(quad&1)*8 + j  (16B contiguous)
    const ushort* Vp = Vt + (size_t)bh * 16384 + (quad >> 1) * 512 + lr * 16 + (quad & 1) * 8;
    // E per lane per X: 8 contiguous bytes at row (q0+X*16+lr), col k0+quad*8
    const unsigned char* Ep0 = et8 + ((size_t)(b * S_ + q0 + lr)) * 512 + quad * 8;
    const unsigned char* Ep1 = Ep0 + (size_t)16 * 512;

    const short8 vones8 = { (short)0x3F80, (short)0x3F80, (short)0x3F80, (short)0x3F80,
                            (short)0x3F80, (short)0x3F80, (short)0x3F80, (short)0x3F80 };

    f32x4 zz = {0.f, 0.f, 0.f, 0.f};
    f32x4 oacc[2][2], lacc[2];
    #pragma unroll
    for (int X = 0; X < 2; X++) { oacc[X][0] = zz; oacc[X][1] = zz; lacc[X] = zz; }

    // prefetch iter 0 (all three streams)
    short8 kf0 = *(const short8*)(Kp);
    short8 kf1 = *(const short8*)(Kp + 128);          // +4 seq rows
    uint2 e0 = *(const uint2*)(Ep0);
    uint2 e1 = *(const uint2*)(Ep1);
    short8 vb0 = *(const short8*)(Vp);
    short8 vb1 = *(const short8*)(Vp + 256);
    Kp += 1024; Ep0 += 32; Ep1 += 32; Vp += 1024;     // advance to iter 1

    #pragma unroll 2
    for (int it = 0; it < 16; ++it) {
        // prefetch next iteration (last-iter read is harmless in-workspace)
        short8 nk0 = *(const short8*)(Kp);
        short8 nk1 = *(const short8*)(Kp + 128);
        uint2 ne0 = *(const uint2*)(Ep0);
        uint2 ne1 = *(const uint2*)(Ep1);
        short8 nv0 = *(const short8*)(Vp);
        short8 nv1 = *(const short8*)(Vp + 256);
        Kp += 1024; Ep0 += 32; Ep1 += 32; Vp += 1024;
        #pragma unroll
        for (int X = 0; X < 2; X++) {
            uint Ea = X ? e1.x : e0.x;
            uint Eb = X ? e1.y : e0.y;
            // bias in C layout: c0[r] = bias[q=lr][k=k0+quad*8+r]; c1: +4
            f32x4 c0 = bsel4v(Ea, tlo, thi);
            f32x4 c1 = bsel4v(Eb, tlo, thi);
            // S^T: s0[r] = S[k=k0+quad*8+r][q=lr] (+bias); s1: +4
            f32x4 s0 = __builtin_amdgcn_mfma_f32_16x16x32_bf16(kf0, qf[X], c0, 0, 0, 0);
            f32x4 s1 = __builtin_amdgcn_mfma_f32_16x16x32_bf16(kf1, qf[X], c1, 0, 0, 0);
            float p0[4], p1[4];
            #pragma unroll
            for (int r = 0; r < 4; r++) {
                p0[r] = EXP2(s0[r]);
                p1[r] = EXP2(s1[r]);
            }
            // PA = native 16x16x32 A-fragment: lane holds P[q=lr][k=quad*8+j]
            union { short8 v; uint u[4]; } PA;
            PA.u[0] = pk_bf16(p0[0], p0[1]); PA.u[1] = pk_bf16(p0[2], p0[3]);
            PA.u[2] = pk_bf16(p1[0], p1[1]); PA.u[3] = pk_bf16(p1[2], p1[3]);
            oacc[X][0] = __builtin_amdgcn_mfma_f32_16x16x32_bf16(PA.v, vb0, oacc[X][0], 0, 0, 0);
            oacc[X][1] = __builtin_amdgcn_mfma_f32_16x16x32_bf16(PA.v, vb1, oacc[X][1], 0, 0, 0);
            lacc[X]    = __builtin_amdgcn_mfma_f32_16x16x32_bf16(PA.v, vones8, lacc[X], 0, 0, 0);
        }
        kf0 = nk0; kf1 = nk1; e0 = ne0; e1 = ne1; vb0 = nv0; vb1 = nv1;
    }

    // lacc[X][r] = full row-sum for q=quad*4+r, replicated across lr lanes
    #pragma unroll
    for (int X = 0; X < 2; X++) {
        #pragma unroll
        for (int r = 0; r < 4; r++) {
            int q = quad * 4 + r;                 // O rows: q, cols d = lr
            float inv = 1.f / lacc[X][r];
            size_t base = (size_t)(b * S_ + q0 + X * 16 + q) * D_ + h * 32;
            o[base + lr]      = f2b(oacc[X][0][r] * inv);
            o[base + 16 + lr] = f2b(oacc[X][1][r] * inv);
        }
    }
}

// ---------------------------------------------------------------------------
// Head (fp32)
__global__ __launch_bounds__(64) void head_kernel(const float* __restrict__ x,
                                                  const float* __restrict__ fc1w,
                                                  const float* __restrict__ fc1b,
                                                  const float* __restrict__ polw,
                                                  const float* __restrict__ polb,
                                                  const float* __restrict__ valw,
                                                  const float* __restrict__ valb,
                                                  float* __restrict__ out)
{
    __shared__ float o1[64];
    int b = blockIdx.x;
    int t = threadIdx.x;
    const float* g = x + (size_t)b * S_ * D_;
    float acc = fc1b[t];
    for (int k = 0; k < D_; k++) acc += g[k] * fc1w[t * D_ + k];
    o1[t] = fmaxf(acc, 0.f);
    __syncthreads();
    if (t < BW_) {
        float a = polb[t];
        for (int k = 0; k < 64; k++) a += o1[k] * polw[t * 64 + k];
        out[b * BW_ + t] = a;
    } else if (t == BW_) {
        float a = valb[0];
        for (int k = 0; k < 64; k++) a += o1[k] * valw[k];
        out[B_ * BW_ + b] = tanhf(a);
    }
}

// ---------------------------------------------------------------------------
extern "C" void kernel_launch(void* const* d_in, const int* in_sizes, int n_in,
                              void* d_out, int out_size, void* d_ws, size_t ws_size,
                              hipStream_t stream)
{
    const int*   cs    = (const int*)d_in[0];
    const int*   etm   = (const int*)d_in[1];
    const float* patch = (const float*)d_in[2];
    const float* game  = (const float*)d_in[3];
    const float* eemb  = (const float*)d_in[4];
    const float* in_w  = (const float*)d_in[5];
    const float* in_b  = (const float*)d_in[6];
    const float* out_w = (const float*)d_in[7];
    const float* out_b = (const float*)d_in[8];
    const float* ff1_w = (const float*)d_in[9];
    const float* ff1_b = (const float*)d_in[10];
    const float* ff2_w = (const float*)d_in[11];
    const float* ff2_b = (const float*)d_in[12];
    const float* ln1_g = (const float*)d_in[13];
    const float* ln1_b = (const float*)d_in[14];
    const float* ln2_g = (const float*)d_in[15];
    const float* ln2_b = (const float*)d_in[16];
    const float* fc1_w = (const float*)d_in[17];
    const float* fc1_b = (const float*)d_in[18];
    const float* pol_w = (const float*)d_in[19];
    const float* pol_b = (const float*)d_in[20];
    const float* val_w = (const float*)d_in[21];
    const float* val_b = (const float*)d_in[22];
    float* out = (float*)d_out;

    char* base = (char*)d_ws;
    float*  x     = (float*)(base + 0);                    // 33554432 B
    ushort* h     = (ushort*)(base + 33554432);            // 16777216 B
    ushort* qkvb  = (ushort*)(base + 50331648);            // 50331648 B (also FF buf)
    ushort* Kb    = (ushort*)(base + 100663296);           // 16777216 B
    ushort* Vt    = (ushort*)(base + 117440512);           // 16777216 B
    ushort* ob    = (ushort*)(base + 134217728);           // 16777216 B
    unsigned char* et8 = (unsigned char*)(base + 150994944); // 16777216 B
    ushort* inwb  = (ushort*)(base + 167772160);           //  1572864 B
    ushort* outwb = (ushort*)(base + 169345024);           //   524288 B
    ushort* ff1wb = (ushort*)(base + 169869312);           //  1048576 B
    ushort* ff2wb = (ushort*)(base + 170917888);           //  1048576 B

    build_et8<<<65536, 256, 0, stream>>>(etm, et8);
    convert_all<<<2048, 256, 0, stream>>>(in_w, out_w, ff1_w, ff2_w,
                                          inwb, outwb, ff1wb, ff2wb);
    // fused build_x + initial LN1 (layer 0); later LNs fused into gemm_ln
    build_ln<<<8192, 256, 0, stream>>>(cs, patch, game, ln1_g, ln1_b, x, h);

    for (int i = 0; i < L_; i++) {
        // qkv GEMM with fused K/V repack (Q -> qkvb, K -> Kb, V^T tiled -> Vt)
        gemm_lds<256, 6, false, true, true><<<1536, 256, 0, stream>>>(
            h, inwb + (size_t)i * 196608, in_b + i * 768, qkvb, Kb, Vt);
        attn_mfma<<<2048, 256, 0, stream>>>(qkvb, Kb, Vt, et8, eemb, ob);
        // out-proj + residual + LN2 -> x (fp32), h (bf16)
        gemm_ln<256><<<512, 256, 0, stream>>>(
            ob, outwb + (size_t)i * 65536, out_b + i * 256, x,
            ln2_g + i * D_, ln2_b + i * D_, h);
        gemm_lds<256, 4, true, false, false><<<1024, 256, 0, stream>>>(
            h, ff1wb + (size_t)i * 131072, ff1_b + i * 512, qkvb, nullptr, nullptr);
        // ff2 + residual + LN1(next layer) -> x (fp32), h (bf16)
        int nx = (i + 1 < L_) ? (i + 1) : i;   // last layer: h unused
        gemm_ln<512><<<512, 256, 0, stream>>>(
            qkvb, ff2wb + (size_t)i * 131072, ff2_b + i * 256, x,
            ln1_g + nx * D_, ln1_b + nx * D_, h);
    }
    head_kernel<<<B_, 64, 0, stream>>>(x, fc1_w, fc1_b, pol_w, pol_b, val_w, val_b, out);
}

// Round 11
// 777.353 us; speedup vs baseline: 1.4902x; 1.4902x over previous
//
#include <hip/hip_runtime.h>
#include <hip/hip_bf16.h>
#include <math.h>

#define L_ 4
#define B_ 64
#define N_ 511
#define D_ 256
#define H_ 8
#define DFF_ 512
#define S_ 512
#define HD_ 32
#define BW_ 7
#define BS_ (B_*S_)   // 32768 rows

typedef __attribute__((ext_vector_type(8))) short short8;   // 8 x bf16 bits
typedef __attribute__((ext_vector_type(4))) short short4v;  // 4 x bf16 bits
typedef __attribute__((ext_vector_type(4))) float f32x4;

#define L2E 1.44269504088896340f
#define QSCL (0.17677669529663687f * 1.44269504088896340f)   // rscale * log2(e)

#if defined(__HIP_DEVICE_COMPILE__) && __has_builtin(__builtin_amdgcn_exp2f)
#define EXP2(x) __builtin_amdgcn_exp2f(x)
#else
#define EXP2(x) exp2f(x)
#endif

__device__ inline ushort f2b(float f) {
    unsigned u = __float_as_uint(f);
    unsigned r = (u + 0x7fffu + ((u >> 16) & 1u)) >> 16;   // RNE
    return (ushort)r;
}

// packed f32x2 -> bf16x2 in one uint (low = a); HW op on gfx950, SW fallback
#if defined(__HIP_DEVICE_COMPILE__) && __has_builtin(__builtin_amdgcn_cvt_pk_bf16_f32)
typedef __attribute__((ext_vector_type(2))) __bf16 bf16x2_t;
__device__ inline uint pk_bf16(float a, float b) {
    bf16x2_t r = __builtin_amdgcn_cvt_pk_bf16_f32(a, b);
    return *(uint*)&r;
}
#else
__device__ inline uint pk_bf16(float a, float b) {
    return (uint)f2b(a) | ((uint)f2b(b) << 16);
}
#endif

// 4-way ADDITIVE bias lookup (log2 domain) returning f32x4 in MFMA C-layout.
// bf16 table via raw v_perm_b32: selectors are BYTE-packed (b = low source,
// idx 0-3; a = high, 4-7).
__device__ inline f32x4 bsel4v(uint E, uint tlo, uint thi) {
    f32x4 r;
#if defined(__HIP_DEVICE_COMPILE__) && __has_builtin(__builtin_amdgcn_perm)
    uint E2  = E + E;                 // per-byte 2e (e<=3: no carry)
    uint E2b = E2 | 0x01010101u;      // per-byte 2e+1
    uint s01 = __builtin_amdgcn_perm(E2b, E2, 0x05010400u);  // [2e0,2e0+1,2e1,2e1+1]
    uint s23 = __builtin_amdgcn_perm(E2b, E2, 0x07030602u);  // [2e2,2e2+1,2e3,2e3+1]
    uint p01 = __builtin_amdgcn_perm(thi, tlo, s01);         // bf16 bl[e0] | bl[e1]<<16
    uint p23 = __builtin_amdgcn_perm(thi, tlo, s23);
    r[0] = __uint_as_float(p01 << 16);
    r[1] = __uint_as_float(p01 & 0xFFFF0000u);
    r[2] = __uint_as_float(p23 << 16);
    r[3] = __uint_as_float(p23 & 0xFFFF0000u);
#else
    #pragma unroll
    for (int i = 0; i < 4; i++) {
        unsigned char e = (unsigned char)((E >> (8 * i)) & 0xff);
        uint bb = e == 0 ? (tlo & 0xFFFFu) : (e == 1 ? (tlo >> 16) :
                  (e == 2 ? (thi & 0xFFFFu) : 0u));
        r[i] = __uint_as_float(bb << 16);
    }
#endif
    return r;
}

// async global->LDS 16B; fallback if builtin missing (host pass)
__device__ inline void gload16(const void* g, void* l) {
#if __has_builtin(__builtin_amdgcn_global_load_lds)
    __builtin_amdgcn_global_load_lds(
        (const __attribute__((address_space(1))) void*)g,
        (__attribute__((address_space(3))) void*)l, 16, 0, 0);
#else
    *(short8*)l = *(const short8*)g;
#endif
}

// ---------------------------------------------------------------------------
// Fused: x = [game_token, patch_emb[cell_states]] (fp32 out) AND h = LN1(x)
// (bf16 out) in one pass. Block = 4 waves, one row per wave.
__global__ __launch_bounds__(256) void build_ln(const int* __restrict__ cs,
                                                const float* __restrict__ patch,
                                                const float* __restrict__ game,
                                                const float* __restrict__ gw,
                                                const float* __restrict__ bw,
                                                float* __restrict__ x,
                                                ushort* __restrict__ h)
{
    int t = threadIdx.x;
    int lane = t & 63;
    int wv = t >> 6;
    int row = blockIdx.x * 4 + wv;            // b*S + s
    int s = row & (S_ - 1);
    float4 v;
    if (s == 0) {
        v = ((const float4*)game)[lane];
    } else {
        int b = row >> 9;
        int cell = cs[b * N_ + s - 1];
        v = ((const float4*)(patch + cell * D_))[lane];
    }
    ((float4*)x)[(size_t)row * 64 + lane] = v;

    float sm = v.x + v.y + v.z + v.w;
    #pragma unroll
    for (int o = 32; o >= 1; o >>= 1) sm += __shfl_xor(sm, o);
    float mean = sm * (1.f / 256.f);
    float dx = v.x - mean, dy = v.y - mean, dz = v.z - mean, dw = v.w - mean;
    float s2 = dx * dx + dy * dy + dz * dz + dw * dw;
    #pragma unroll
    for (int o = 32; o >= 1; o >>= 1) s2 += __shfl_xor(s2, o);
    float rstd = rsqrtf(s2 * (1.f / 256.f) + 1e-5f);
    float4 g  = *(const float4*)(gw + lane * 4);
    float4 bb = *(const float4*)(bw + lane * 4);
    ushort4 o4;
    o4.x = f2b(dx * rstd * g.x + bb.x);
    o4.y = f2b(dy * rstd * g.y + bb.y);
    o4.z = f2b(dz * rstd * g.z + bb.z);
    o4.w = f2b(dw * rstd * g.w + bb.w);
    *(ushort4*)(h + (size_t)row * D_ + lane * 4) = o4;
}

// ---------------------------------------------------------------------------
// et8[b][q][k] = (q>0 && k>0) ? et[b][q-1][k-1] : 3   (3 -> bias 0)
// R7-proven scalar version (the R9/R10 vectorized variant never benched;
// two container failures — retreat to known-good code).
__global__ __launch_bounds__(256) void build_et8(const int* __restrict__ et,
                                                 unsigned char* __restrict__ et8)
{
    long idx = (long)blockIdx.x * 256 + threadIdx.x;  // over B*S*S
    int k = (int)(idx & (S_ - 1));
    long rem = idx >> 9;                              // b*S + q
    int q = (int)(rem & (S_ - 1));
    int b = (int)(rem >> 9);
    unsigned char v = 3;
    if (q > 0 && k > 0) {
        v = (unsigned char)et[((long)b * N_ + (q - 1)) * N_ + (k - 1)];
    }
    et8[idx] = v;
}

// ---------------------------------------------------------------------------
// All weight conversions in ONE kernel.
__global__ __launch_bounds__(256) void convert_all(const float* __restrict__ in_w,
                                                   const float* __restrict__ out_w,
                                                   const float* __restrict__ ff1_w,
                                                   const float* __restrict__ ff2_w,
                                                   ushort* __restrict__ inwb,
                                                   ushort* __restrict__ outwb,
                                                   ushort* __restrict__ ff1wb,
                                                   ushort* __restrict__ ff2wb)
{
    int i = blockIdx.x * 256 + threadIdx.x;   // 0 .. 524287
    const float* src;
    ushort* dst;
    int j;
    float s = 1.f;
    if (i < 196608) {
        j = i; src = in_w; dst = inwb;
        int r = (j >> 6) % 768;               // 64 float4s per 256-col row
        if (r < 256) s = (float)QSCL;
    } else if (i < 262144) {
        j = i - 196608; src = out_w; dst = outwb;
    } else if (i < 393216) {
        j = i - 262144; src = ff1_w; dst = ff1wb;
    } else {
        j = i - 393216; src = ff2_w; dst = ff2wb;
    }
    float4 v = ((const float4*)src)[j];
    ushort4 o4;
    o4.x = f2b(v.x * s); o4.y = f2b(v.y * s); o4.z = f2b(v.z * s); o4.w = f2b(v.w * s);
    ((ushort4*)dst)[j] = o4;
}

// ---------------------------------------------------------------------------
// m97-style LDS GEMM, BK=64 via TWO [128][32] k-half planes (halves the
// barrier-drain count; split planes keep ds_reads conflict-free).
template<int K, int NT, bool RELU, bool QSC, bool QKV>
__global__ __launch_bounds__(256, 2) void gemm_lds(const ushort* __restrict__ A,
                                                   const ushort* __restrict__ W,
                                                   const float* __restrict__ bias,
                                                   ushort* __restrict__ Cout,
                                                   ushort* __restrict__ Kb,
                                                   ushort* __restrict__ Vt)
{
    __shared__ ushort As[2][4096];    // [khalf][128 rows x 32]
    __shared__ ushort Ws[2][4096];
    const int N = NT * 128;
    int t = threadIdx.x;
    int wave = t >> 6, lane = t & 63;
    int lr = lane & 15, quad = lane >> 4;
    int lk = quad * 8;
    int blk = blockIdx.x;                      // grid = NT*256
    int xcd = blk & 7, idx = blk >> 3;
    int m0 = (xcd * 32 + (idx & 31)) * 128;
    int n0 = (idx >> 5) * 128;
    int mh = (wave >> 1) * 64, nh = (wave & 1) * 64;

    const ushort* ga0 = A + (size_t)(m0 + (t >> 2)) * K + (t & 3) * 8;
    const ushort* ga1 = ga0 + (size_t)64 * K;
    const ushort* gw0 = W + (size_t)(n0 + (t >> 2)) * K + (t & 3) * 8;
    const ushort* gw1 = gw0 + (size_t)64 * K;
    int t8 = t * 8;

    f32x4 acc[4][4];
    f32x4 zz = {0.f, 0.f, 0.f, 0.f};
    #pragma unroll
    for (int i = 0; i < 4; i++)
        #pragma unroll
        for (int j = 0; j < 4; j++) acc[i][j] = zz;

    for (int k0 = 0; k0 < K; k0 += 64) {
        gload16(ga0 + k0,      &As[0][t8]);
        gload16(ga1 + k0,      &As[0][t8 + 2048]);
        gload16(ga0 + k0 + 32, &As[1][t8]);
        gload16(ga1 + k0 + 32, &As[1][t8 + 2048]);
        gload16(gw0 + k0,      &Ws[0][t8]);
        gload16(gw1 + k0,      &Ws[0][t8 + 2048]);
        gload16(gw0 + k0 + 32, &Ws[1][t8]);
        gload16(gw1 + k0 + 32, &Ws[1][t8 + 2048]);
        __syncthreads();
        short8 af[2][4], wf[2][4];
        #pragma unroll
        for (int kk = 0; kk < 2; kk++) {
            #pragma unroll
            for (int i = 0; i < 4; i++) af[kk][i] = *(const short8*)&As[kk][(mh + i * 16 + lr) * 32 + lk];
            #pragma unroll
            for (int j = 0; j < 4; j++) wf[kk][j] = *(const short8*)&Ws[kk][(nh + j * 16 + lr) * 32 + lk];
        }
        #pragma unroll
        for (int kk = 0; kk < 2; kk++)
            #pragma unroll
            for (int i = 0; i < 4; i++)
                #pragma unroll
                for (int j = 0; j < 4; j++)
                    acc[i][j] = __builtin_amdgcn_mfma_f32_16x16x32_bf16(af[kk][i], wf[kk][j], acc[i][j], 0, 0, 0);
        __syncthreads();
    }

    #pragma unroll
    for (int nt = 0; nt < 4; nt++) {
        int colbase = n0 + nh + nt * 16;       // 16-aligned; regions 256-aligned
        int col = colbase + lr;
        float bv = bias[col];
        if (QSC && colbase < 256) bv *= (float)QSCL;
        int region = QKV ? (colbase >> 8) : 0; // wave-uniform
        #pragma unroll
        for (int mt = 0; mt < 4; mt++) {
            int rowb = m0 + mh + mt * 16 + quad * 4;
            if (!QKV || region == 0) {
                #pragma unroll
                for (int r = 0; r < 4; r++) {
                    size_t cidx = (size_t)(rowb + r) * N + col;
                    float v = acc[mt][nt][r] + bv;
                    if (RELU) v = fmaxf(v, 0.f);
                    Cout[cidx] = f2b(v);
                }
            } else if (region == 1) {          // K -> Kb[b,h,s,32]
                int hh = (col >> 5) & 7, d = col & 31;
                int bb = rowb >> 9, s = rowb & 511;
                size_t kbase = ((size_t)(bb * 8 + hh) * 512 + s) * 32 + d;
                #pragma unroll
                for (int r = 0; r < 4; r++)
                    Kb[kbase + (size_t)r * 32] = f2b(acc[mt][nt][r] + bv);
            } else {                           // V -> Vt[bh][s/16][d][16] tiled
                int hh = (col >> 5) & 7, d = col & 31;
                int bb = rowb >> 9, s = rowb & 511;
                ushort4 w;
                w.x = f2b(acc[mt][nt][0] + bv);
                w.y = f2b(acc[mt][nt][1] + bv);
                w.z = f2b(acc[mt][nt][2] + bv);
                w.w = f2b(acc[mt][nt][3] + bv);
                size_t vidx = (((size_t)(bb * 8 + hh) * 32 + (s >> 4)) * 32 + d) * 16 + (s & 15);
                *(ushort4*)&Vt[vidx] = w;
            }
        }
    }
}

// ---------------------------------------------------------------------------
// Fused residual GEMM + LayerNorm, BK=64 via two k-half planes.
// Block = 64 rows x 256 cols; grid 512, (256,2).
template<int K>
__global__ __launch_bounds__(256, 2) void gemm_ln(const ushort* __restrict__ A,
                                                  const ushort* __restrict__ W,
                                                  const float* __restrict__ bias,
                                                  float* __restrict__ X,
                                                  const float* __restrict__ lng,
                                                  const float* __restrict__ lnb,
                                                  ushort* __restrict__ Hout)
{
    __shared__ ushort As[2][2048];      //  8 KB  [khalf][64 x 32]
    __shared__ ushort Ws[2][8192];      // 32 KB  [khalf][256 x 32]
    __shared__ float lds_s[64][4];      //  1 KB
    __shared__ float lds_q[64][4];      //  1 KB
    int t = threadIdx.x;
    int wave = t >> 6, lane = t & 63;
    int lr = lane & 15, quad = lane >> 4;
    int lk = quad * 8;
    int blk = blockIdx.x;               // grid 512
    int xcd = blk & 7;
    int m0 = (xcd * 64 + (blk >> 3)) * 64;
    int nh = wave * 64;

    const ushort* ga = A + (size_t)(m0 + (t >> 2)) * K + (t & 3) * 8;
    const ushort* gw = W + (size_t)(t >> 2) * K + (t & 3) * 8;
    int t8 = t * 8;

    f32x4 acc[4][4];
    f32x4 zz = {0.f, 0.f, 0.f, 0.f};
    #pragma unroll
    for (int i = 0; i < 4; i++)
        #pragma unroll
        for (int j = 0; j < 4; j++) acc[i][j] = zz;

    for (int k0 = 0; k0 < K; k0 += 64) {
        gload16(ga + k0,      &As[0][t8]);
        gload16(ga + k0 + 32, &As[1][t8]);
        #pragma unroll
        for (int j = 0; j < 4; j++) {
            gload16(gw + (size_t)(j * 64) * K + k0,      &Ws[0][t8 + j * 2048]);
            gload16(gw + (size_t)(j * 64) * K + k0 + 32, &Ws[1][t8 + j * 2048]);
        }
        __syncthreads();
        short8 af[2][4], wf[2][4];
        #pragma unroll
        for (int kk = 0; kk < 2; kk++) {
            #pragma unroll
            for (int i = 0; i < 4; i++) af[kk][i] = *(const short8*)&As[kk][(i * 16 + lr) * 32 + lk];
            #pragma unroll
            for (int j = 0; j < 4; j++) wf[kk][j] = *(const short8*)&Ws[kk][(nh + j * 16 + lr) * 32 + lk];
        }
        #pragma unroll
        for (int kk = 0; kk < 2; kk++)
            #pragma unroll
            for (int i = 0; i < 4; i++)
                #pragma unroll
                for (int j = 0; j < 4; j++)
                    acc[i][j] = __builtin_amdgcn_mfma_f32_16x16x32_bf16(af[kk][i], wf[kk][j], acc[i][j], 0, 0, 0);
        __syncthreads();
    }

    // epilogue pass 1: v = acc + bias + X; store X; keep v in acc; row partials
    float gc[4], bc[4], bi[4];
    #pragma unroll
    for (int nt = 0; nt < 4; nt++) {
        int col = nh + nt * 16 + lr;
        gc[nt] = lng[col]; bc[nt] = lnb[col]; bi[nt] = bias[col];
    }
    float psum[16], psq[16];
    #pragma unroll
    for (int e = 0; e < 16; e++) { psum[e] = 0.f; psq[e] = 0.f; }
    #pragma unroll
    for (int nt = 0; nt < 4; nt++) {
        #pragma unroll
        for (int mt = 0; mt < 4; mt++) {
            #pragma unroll
            for (int r = 0; r < 4; r++) {
                int row = m0 + mt * 16 + quad * 4 + r;
                size_t idx = (size_t)row * D_ + nh + nt * 16 + lr;
                float v = acc[mt][nt][r] + bi[nt] + X[idx];
                X[idx] = v;
                acc[mt][nt][r] = v;
                psum[mt * 4 + r] += v;
                psq[mt * 4 + r]  += v * v;
            }
        }
    }
    // reduce over lr (16 lanes per quad hold disjoint cols of same rows)
    #pragma unroll
    for (int e = 0; e < 16; e++) {
        float s = psum[e], q = psq[e];
        s += __shfl_xor(s, 1); q += __shfl_xor(q, 1);
        s += __shfl_xor(s, 2); q += __shfl_xor(q, 2);
        s += __shfl_xor(s, 4); q += __shfl_xor(q, 4);
        s += __shfl_xor(s, 8); q += __shfl_xor(q, 8);
        psum[e] = s; psq[e] = q;
    }
    if (lr == 0) {
        #pragma unroll
        for (int mt = 0; mt < 4; mt++)
            #pragma unroll
            for (int r = 0; r < 4; r++) {
                int rl = mt * 16 + quad * 4 + r;
                lds_s[rl][wave] = psum[mt * 4 + r];
                lds_q[rl][wave] = psq[mt * 4 + r];
            }
    }
    __syncthreads();
    // epilogue pass 2: finalize stats, write h
    #pragma unroll
    for (int mt = 0; mt < 4; mt++) {
        #pragma unroll
        for (int r = 0; r < 4; r++) {
            int rl = mt * 16 + quad * 4 + r;
            f32x4 ss = *(const f32x4*)lds_s[rl];
            f32x4 qq = *(const f32x4*)lds_q[rl];
            float s = ss[0] + ss[1] + ss[2] + ss[3];
            float q = qq[0] + qq[1] + qq[2] + qq[3];
            float mean = s * (1.f / 256.f);
            float rstd = rsqrtf(q * (1.f / 256.f) - mean * mean + 1e-5f);
            int row = m0 + mt * 16 + quad * 4 + r;
            #pragma unroll
            for (int nt = 0; nt < 4; nt++) {
                size_t idx = (size_t)row * D_ + nh + nt * 16 + lr;
                float hv = (acc[mt][nt][r] - mean) * rstd * gc[nt] + bc[nt];
                Hout[idx] = f2b(hv);
            }
        }
    }
}

// ---------------------------------------------------------------------------
// Flash attention, barrier-free (R7 proven config): no LDS, E in registers,
// PV on K=32 MFMA, full-stream prefetch + linear pointers, (256,4).
// R8 lesson: real register need ≈ 76 (52 arch + ~24 acc in the unified file)
// -> the 65-128 bucket -> 4 blocks/CU is the HW ceiling for this structure;
// (256,8) forces <=64 total and spills ~355 MB/dispatch. Do not raise.
__global__ __launch_bounds__(256, 4) void attn_mfma(const ushort* __restrict__ qkv,
                                                    const ushort* __restrict__ Kb,
                                                    const ushort* __restrict__ Vt,
                                                    const unsigned char* __restrict__ et8,
                                                    const float* __restrict__ eemb,
                                                    ushort* __restrict__ o)
{
    int t = threadIdx.x;
    int wave = t >> 6, lane = t & 63;
    int lr = lane & 15, quad = lane >> 4;
    int lk = quad * 8;
    int blk = blockIdx.x;                    // grid 2048
    int b = ((blk >> 8) << 3) | (blk & 7);   // same-b blocks -> same XCD
    int h = (blk >> 3) & 7;
    int qq = (blk >> 6) & 3;
    int bh = b * 8 + h;
    int q0 = qq * 128 + wave * 32;
    // additive bias table (log2 domain): exp2(s + b*L2E)
    float eb0 = eemb[h] * L2E, eb1 = eemb[8 + h] * L2E, eb2 = eemb[16 + h] * L2E;
    uint tlo = (uint)f2b(eb0) | ((uint)f2b(eb1) << 16);
    uint thi = (uint)f2b(eb2);               // high half = bf16 0.0 for e==3

    short8 qf[2];
    #pragma unroll
    for (int X = 0; X < 2; X++)
        qf[X] = *(const short8*)(qkv + ((size_t)(b * S_ + q0 + X * 16 + lr)) * 768 + h * 32 + lk);
    // permuted K pointer: A row m=lr holds K seq g(lr) = (lr>>2)*8 + (lr&3)
    int gl = ((lr >> 2) << 3) | (lr & 3);
    const ushort* Kp = Kb + ((size_t)(bh * S_) + gl) * 32 + lk;
    // V B-fragment (16x16x32): lane needs V[k0+quad*8+j][d=lr], j=0..7
    //  = Vt tile (k0>>4)+(quad>>1), d=lr, sl=(quad&1)*8 + j  (16B contiguous)
    const ushort* Vp = Vt + (size_t)bh * 16384 + (quad >> 1) * 512 + lr * 16 + (quad & 1) * 8;
    // E per lane per X: 8 contiguous bytes at row (q0+X*16+lr), col k0+quad*8
    const unsigned char* Ep0 = et8 + ((size_t)(b * S_ + q0 + lr)) * 512 + quad * 8;
    const unsigned char* Ep1 = Ep0 + (size_t)16 * 512;

    const short8 vones8 = { (short)0x3F80, (short)0x3F80, (short)0x3F80, (short)0x3F80,
                            (short)0x3F80, (short)0x3F80, (short)0x3F80, (short)0x3F80 };

    f32x4 zz = {0.f, 0.f, 0.f, 0.f};
    f32x4 oacc[2][2], lacc[2];
    #pragma unroll
    for (int X = 0; X < 2; X++) { oacc[X][0] = zz; oacc[X][1] = zz; lacc[X] = zz; }

    // prefetch iter 0 (all three streams)
    short8 kf0 = *(const short8*)(Kp);
    short8 kf1 = *(const short8*)(Kp + 128);          // +4 seq rows
    uint2 e0 = *(const uint2*)(Ep0);
    uint2 e1 = *(const uint2*)(Ep1);
    short8 vb0 = *(const short8*)(Vp);
    short8 vb1 = *(const short8*)(Vp + 256);
    Kp += 1024; Ep0 += 32; Ep1 += 32; Vp += 1024;     // advance to iter 1

    #pragma unroll 2
    for (int it = 0; it < 16; ++it) {
        // prefetch next iteration (last-iter read is harmless in-workspace)
        short8 nk0 = *(const short8*)(Kp);
        short8 nk1 = *(const short8*)(Kp + 128);
        uint2 ne0 = *(const uint2*)(Ep0);
        uint2 ne1 = *(const uint2*)(Ep1);
        short8 nv0 = *(const short8*)(Vp);
        short8 nv1 = *(const short8*)(Vp + 256);
        Kp += 1024; Ep0 += 32; Ep1 += 32; Vp += 1024;
        #pragma unroll
        for (int X = 0; X < 2; X++) {
            uint Ea = X ? e1.x : e0.x;
            uint Eb = X ? e1.y : e0.y;
            // bias in C layout: c0[r] = bias[q=lr][k=k0+quad*8+r]; c1: +4
            f32x4 c0 = bsel4v(Ea, tlo, thi);
            f32x4 c1 = bsel4v(Eb, tlo, thi);
            // S^T: s0[r] = S[k=k0+quad*8+r][q=lr] (+bias); s1: +4
            f32x4 s0 = __builtin_amdgcn_mfma_f32_16x16x32_bf16(kf0, qf[X], c0, 0, 0, 0);
            f32x4 s1 = __builtin_amdgcn_mfma_f32_16x16x32_bf16(kf1, qf[X], c1, 0, 0, 0);
            float p0[4], p1[4];
            #pragma unroll
            for (int r = 0; r < 4; r++) {
                p0[r] = EXP2(s0[r]);
                p1[r] = EXP2(s1[r]);
            }
            // PA = native 16x16x32 A-fragment: lane holds P[q=lr][k=quad*8+j]
            union { short8 v; uint u[4]; } PA;
            PA.u[0] = pk_bf16(p0[0], p0[1]); PA.u[1] = pk_bf16(p0[2], p0[3]);
            PA.u[2] = pk_bf16(p1[0], p1[1]); PA.u[3] = pk_bf16(p1[2], p1[3]);
            oacc[X][0] = __builtin_amdgcn_mfma_f32_16x16x32_bf16(PA.v, vb0, oacc[X][0], 0, 0, 0);
            oacc[X][1] = __builtin_amdgcn_mfma_f32_16x16x32_bf16(PA.v, vb1, oacc[X][1], 0, 0, 0);
            lacc[X]    = __builtin_amdgcn_mfma_f32_16x16x32_bf16(PA.v, vones8, lacc[X], 0, 0, 0);
        }
        kf0 = nk0; kf1 = nk1; e0 = ne0; e1 = ne1; vb0 = nv0; vb1 = nv1;
    }

    // lacc[X][r] = full row-sum for q=quad*4+r, replicated across lr lanes
    #pragma unroll
    for (int X = 0; X < 2; X++) {
        #pragma unroll
        for (int r = 0; r < 4; r++) {
            int q = quad * 4 + r;                 // O rows: q, cols d = lr
            float inv = 1.f / lacc[X][r];
            size_t base = (size_t)(b * S_ + q0 + X * 16 + q) * D_ + h * 32;
            o[base + lr]      = f2b(oacc[X][0][r] * inv);
            o[base + 16 + lr] = f2b(oacc[X][1][r] * inv);
        }
    }
}

// ---------------------------------------------------------------------------
// Head (fp32)
__global__ __launch_bounds__(64) void head_kernel(const float* __restrict__ x,
                                                  const float* __restrict__ fc1w,
                                                  const float* __restrict__ fc1b,
                                                  const float* __restrict__ polw,
                                                  const float* __restrict__ polb,
                                                  const float* __restrict__ valw,
                                                  const float* __restrict__ valb,
                                                  float* __restrict__ out)
{
    __shared__ float o1[64];
    int b = blockIdx.x;
    int t = threadIdx.x;
    const float* g = x + (size_t)b * S_ * D_;
    float acc = fc1b[t];
    for (int k = 0; k < D_; k++) acc += g[k] * fc1w[t * D_ + k];
    o1[t] = fmaxf(acc, 0.f);
    __syncthreads();
    if (t < BW_) {
        float a = polb[t];
        for (int k = 0; k < 64; k++) a += o1[k] * polw[t * 64 + k];
        out[b * BW_ + t] = a;
    } else if (t == BW_) {
        float a = valb[0];
        for (int k = 0; k < 64; k++) a += o1[k] * valw[k];
        out[B_ * BW_ + b] = tanhf(a);
    }
}

// ---------------------------------------------------------------------------
extern "C" void kernel_launch(void* const* d_in, const int* in_sizes, int n_in,
                              void* d_out, int out_size, void* d_ws, size_t ws_size,
                              hipStream_t stream)
{
    const int*   cs    = (const int*)d_in[0];
    const int*   etm   = (const int*)d_in[1];
    const float* patch = (const float*)d_in[2];
    const float* game  = (const float*)d_in[3];
    const float* eemb  = (const float*)d_in[4];
    const float* in_w  = (const float*)d_in[5];
    const float* in_b  = (const float*)d_in[6];
    const float* out_w = (const float*)d_in[7];
    const float* out_b = (const float*)d_in[8];
    const float* ff1_w = (const float*)d_in[9];
    const float* ff1_b = (const float*)d_in[10];
    const float* ff2_w = (const float*)d_in[11];
    const float* ff2_b = (const float*)d_in[12];
    const float* ln1_g = (const float*)d_in[13];
    const float* ln1_b = (const float*)d_in[14];
    const float* ln2_g = (const float*)d_in[15];
    const float* ln2_b = (const float*)d_in[16];
    const float* fc1_w = (const float*)d_in[17];
    const float* fc1_b = (const float*)d_in[18];
    const float* pol_w = (const float*)d_in[19];
    const float* pol_b = (const float*)d_in[20];
    const float* val_w = (const float*)d_in[21];
    const float* val_b = (const float*)d_in[22];
    float* out = (float*)d_out;

    char* base = (char*)d_ws;
    float*  x     = (float*)(base + 0);                    // 33554432 B
    ushort* h     = (ushort*)(base + 33554432);            // 16777216 B
    ushort* qkvb  = (ushort*)(base + 50331648);            // 50331648 B (also FF buf)
    ushort* Kb    = (ushort*)(base + 100663296);           // 16777216 B
    ushort* Vt    = (ushort*)(base + 117440512);           // 16777216 B
    ushort* ob    = (ushort*)(base + 134217728);           // 16777216 B
    unsigned char* et8 = (unsigned char*)(base + 150994944); // 16777216 B
    ushort* inwb  = (ushort*)(base + 167772160);           //  1572864 B
    ushort* outwb = (ushort*)(base + 169345024);           //   524288 B
    ushort* ff1wb = (ushort*)(base + 169869312);           //  1048576 B
    ushort* ff2wb = (ushort*)(base + 170917888);           //  1048576 B

    build_et8<<<65536, 256, 0, stream>>>(etm, et8);
    convert_all<<<2048, 256, 0, stream>>>(in_w, out_w, ff1_w, ff2_w,
                                          inwb, outwb, ff1wb, ff2wb);
    // fused build_x + initial LN1 (layer 0); later LNs fused into gemm_ln
    build_ln<<<8192, 256, 0, stream>>>(cs, patch, game, ln1_g, ln1_b, x, h);

    for (int i = 0; i < L_; i++) {
        // qkv GEMM with fused K/V repack (Q -> qkvb, K -> Kb, V^T tiled -> Vt)
        gemm_lds<256, 6, false, true, true><<<1536, 256, 0, stream>>>(
            h, inwb + (size_t)i * 196608, in_b + i * 768, qkvb, Kb, Vt);
        attn_mfma<<<2048, 256, 0, stream>>>(qkvb, Kb, Vt, et8, eemb, ob);
        // out-proj + residual + LN2 -> x (fp32), h (bf16)
        gemm_ln<256><<<512, 256, 0, stream>>>(
            ob, outwb + (size_t)i * 65536, out_b + i * 256, x,
            ln2_g + i * D_, ln2_b + i * D_, h);
        gemm_lds<256, 4, true, false, false><<<1024, 256, 0, stream>>>(
            h, ff1wb + (size_t)i * 131072, ff1_b + i * 512, qkvb, nullptr, nullptr);
        // ff2 + residual + LN1(next layer) -> x (fp32), h (bf16)
        int nx = (i + 1 < L_) ? (i + 1) : i;   // last layer: h unused
        gemm_ln<512><<<512, 256, 0, stream>>>(
            qkvb, ff2wb + (size_t)i * 131072, ff2_b + i * 256, x,
            ln1_g + nx * D_, ln1_b + nx * D_, h);
    }
    head_kernel<<<B_, 64, 0, stream>>>(x, fc1_w, fc1_b, pol_w, pol_b, val_w, val_b, out);
}

// Round 12
// 689.656 us; speedup vs baseline: 1.6797x; 1.1272x over previous
//
#include <hip/hip_runtime.h>
#include <hip/hip_bf16.h>
#include <math.h>

#define L_ 4
#define B_ 64
#define N_ 511
#define D_ 256
#define H_ 8
#define DFF_ 512
#define S_ 512
#define HD_ 32
#define BW_ 7
#define BS_ (B_*S_)   // 32768 rows

typedef __attribute__((ext_vector_type(8))) short short8;   // 8 x bf16 bits
typedef __attribute__((ext_vector_type(4))) short short4v;  // 4 x bf16 bits
typedef __attribute__((ext_vector_type(4))) float f32x4;

#define L2E 1.44269504088896340f
#define QSCL (0.17677669529663687f * 1.44269504088896340f)   // rscale * log2(e)

#if defined(__HIP_DEVICE_COMPILE__) && __has_builtin(__builtin_amdgcn_exp2f)
#define EXP2(x) __builtin_amdgcn_exp2f(x)
#else
#define EXP2(x) exp2f(x)
#endif

__device__ inline ushort f2b(float f) {
    unsigned u = __float_as_uint(f);
    unsigned r = (u + 0x7fffu + ((u >> 16) & 1u)) >> 16;   // RNE
    return (ushort)r;
}

__device__ inline float b2f(ushort u) {
    return __uint_as_float(((uint)u) << 16);
}

// packed f32x2 -> bf16x2 in one uint (low = a); HW op on gfx950, SW fallback
#if defined(__HIP_DEVICE_COMPILE__) && __has_builtin(__builtin_amdgcn_cvt_pk_bf16_f32)
typedef __attribute__((ext_vector_type(2))) __bf16 bf16x2_t;
__device__ inline uint pk_bf16(float a, float b) {
    bf16x2_t r = __builtin_amdgcn_cvt_pk_bf16_f32(a, b);
    return *(uint*)&r;
}
#else
__device__ inline uint pk_bf16(float a, float b) {
    return (uint)f2b(a) | ((uint)f2b(b) << 16);
}
#endif

// 4-way ADDITIVE bias lookup (log2 domain) returning f32x4 in MFMA C-layout.
// bf16 table via raw v_perm_b32: selectors are BYTE-packed (b = low source,
// idx 0-3; a = high, 4-7).
__device__ inline f32x4 bsel4v(uint E, uint tlo, uint thi) {
    f32x4 r;
#if defined(__HIP_DEVICE_COMPILE__) && __has_builtin(__builtin_amdgcn_perm)
    uint E2  = E + E;                 // per-byte 2e (e<=3: no carry)
    uint E2b = E2 | 0x01010101u;      // per-byte 2e+1
    uint s01 = __builtin_amdgcn_perm(E2b, E2, 0x05010400u);  // [2e0,2e0+1,2e1,2e1+1]
    uint s23 = __builtin_amdgcn_perm(E2b, E2, 0x07030602u);  // [2e2,2e2+1,2e3,2e3+1]
    uint p01 = __builtin_amdgcn_perm(thi, tlo, s01);         // bf16 bl[e0] | bl[e1]<<16
    uint p23 = __builtin_amdgcn_perm(thi, tlo, s23);
    r[0] = __uint_as_float(p01 << 16);
    r[1] = __uint_as_float(p01 & 0xFFFF0000u);
    r[2] = __uint_as_float(p23 << 16);
    r[3] = __uint_as_float(p23 & 0xFFFF0000u);
#else
    #pragma unroll
    for (int i = 0; i < 4; i++) {
        unsigned char e = (unsigned char)((E >> (8 * i)) & 0xff);
        uint bb = e == 0 ? (tlo & 0xFFFFu) : (e == 1 ? (tlo >> 16) :
                  (e == 2 ? (thi & 0xFFFFu) : 0u));
        r[i] = __uint_as_float(bb << 16);
    }
#endif
    return r;
}

// async global->LDS 16B; fallback if builtin missing (host pass)
__device__ inline void gload16(const void* g, void* l) {
#if __has_builtin(__builtin_amdgcn_global_load_lds)
    __builtin_amdgcn_global_load_lds(
        (const __attribute__((address_space(1))) void*)g,
        (__attribute__((address_space(3))) void*)l, 16, 0, 0);
#else
    *(short8*)l = *(const short8*)g;
#endif
}

// ---------------------------------------------------------------------------
// Fused: x = [game_token, patch_emb[cell_states]] (fp32 out) AND h = LN1(x)
// (bf16 out) in one pass. Block = 4 waves, one row per wave.
__global__ __launch_bounds__(256) void build_ln(const int* __restrict__ cs,
                                                const float* __restrict__ patch,
                                                const float* __restrict__ game,
                                                const float* __restrict__ gw,
                                                const float* __restrict__ bw,
                                                float* __restrict__ x,
                                                ushort* __restrict__ h)
{
    int t = threadIdx.x;
    int lane = t & 63;
    int wv = t >> 6;
    int row = blockIdx.x * 4 + wv;            // b*S + s
    int s = row & (S_ - 1);
    float4 v;
    if (s == 0) {
        v = ((const float4*)game)[lane];
    } else {
        int b = row >> 9;
        int cell = cs[b * N_ + s - 1];
        v = ((const float4*)(patch + cell * D_))[lane];
    }
    ((float4*)x)[(size_t)row * 64 + lane] = v;

    float sm = v.x + v.y + v.z + v.w;
    #pragma unroll
    for (int o = 32; o >= 1; o >>= 1) sm += __shfl_xor(sm, o);
    float mean = sm * (1.f / 256.f);
    float dx = v.x - mean, dy = v.y - mean, dz = v.z - mean, dw = v.w - mean;
    float s2 = dx * dx + dy * dy + dz * dz + dw * dw;
    #pragma unroll
    for (int o = 32; o >= 1; o >>= 1) s2 += __shfl_xor(s2, o);
    float rstd = rsqrtf(s2 * (1.f / 256.f) + 1e-5f);
    float4 g  = *(const float4*)(gw + lane * 4);
    float4 bb = *(const float4*)(bw + lane * 4);
    ushort4 o4;
    o4.x = f2b(dx * rstd * g.x + bb.x);
    o4.y = f2b(dy * rstd * g.y + bb.y);
    o4.z = f2b(dz * rstd * g.z + bb.z);
    o4.w = f2b(dw * rstd * g.w + bb.w);
    *(ushort4*)(h + (size_t)row * D_ + lane * 4) = o4;
}

// ---------------------------------------------------------------------------
// et8[b][q][k] = (q>0 && k>0) ? et[b][q-1][k-1] : 3   (3 -> bias 0)
__global__ __launch_bounds__(256) void build_et8(const int* __restrict__ et,
                                                 unsigned char* __restrict__ et8)
{
    long idx = (long)blockIdx.x * 256 + threadIdx.x;  // over B*S*S
    int k = (int)(idx & (S_ - 1));
    long rem = idx >> 9;                              // b*S + q
    int q = (int)(rem & (S_ - 1));
    int b = (int)(rem >> 9);
    unsigned char v = 3;
    if (q > 0 && k > 0) {
        v = (unsigned char)et[((long)b * N_ + (q - 1)) * N_ + (k - 1)];
    }
    et8[idx] = v;
}

// ---------------------------------------------------------------------------
// All weight conversions in ONE kernel.
__global__ __launch_bounds__(256) void convert_all(const float* __restrict__ in_w,
                                                   const float* __restrict__ out_w,
                                                   const float* __restrict__ ff1_w,
                                                   const float* __restrict__ ff2_w,
                                                   ushort* __restrict__ inwb,
                                                   ushort* __restrict__ outwb,
                                                   ushort* __restrict__ ff1wb,
                                                   ushort* __restrict__ ff2wb)
{
    int i = blockIdx.x * 256 + threadIdx.x;   // 0 .. 524287
    const float* src;
    ushort* dst;
    int j;
    float s = 1.f;
    if (i < 196608) {
        j = i; src = in_w; dst = inwb;
        int r = (j >> 6) % 768;               // 64 float4s per 256-col row
        if (r < 256) s = (float)QSCL;
    } else if (i < 262144) {
        j = i - 196608; src = out_w; dst = outwb;
    } else if (i < 393216) {
        j = i - 262144; src = ff1_w; dst = ff1wb;
    } else {
        j = i - 393216; src = ff2_w; dst = ff2wb;
    }
    float4 v = ((const float4*)src)[j];
    ushort4 o4;
    o4.x = f2b(v.x * s); o4.y = f2b(v.y * s); o4.z = f2b(v.z * s); o4.w = f2b(v.w * s);
    ((ushort4*)dst)[j] = o4;
}

// ---------------------------------------------------------------------------
// m97-style LDS GEMM, BK=64 via TWO [128][32] k-half planes (halves the
// barrier-drain count; split planes keep ds_reads conflict-free).
template<int K, int NT, bool RELU, bool QSC, bool QKV>
__global__ __launch_bounds__(256, 2) void gemm_lds(const ushort* __restrict__ A,
                                                   const ushort* __restrict__ W,
                                                   const float* __restrict__ bias,
                                                   ushort* __restrict__ Cout,
                                                   ushort* __restrict__ Kb,
                                                   ushort* __restrict__ Vt)
{
    __shared__ ushort As[2][4096];    // [khalf][128 rows x 32]
    __shared__ ushort Ws[2][4096];
    const int N = NT * 128;
    int t = threadIdx.x;
    int wave = t >> 6, lane = t & 63;
    int lr = lane & 15, quad = lane >> 4;
    int lk = quad * 8;
    int blk = blockIdx.x;                      // grid = NT*256
    int xcd = blk & 7, idx = blk >> 3;
    int m0 = (xcd * 32 + (idx & 31)) * 128;
    int n0 = (idx >> 5) * 128;
    int mh = (wave >> 1) * 64, nh = (wave & 1) * 64;

    const ushort* ga0 = A + (size_t)(m0 + (t >> 2)) * K + (t & 3) * 8;
    const ushort* ga1 = ga0 + (size_t)64 * K;
    const ushort* gw0 = W + (size_t)(n0 + (t >> 2)) * K + (t & 3) * 8;
    const ushort* gw1 = gw0 + (size_t)64 * K;
    int t8 = t * 8;

    f32x4 acc[4][4];
    f32x4 zz = {0.f, 0.f, 0.f, 0.f};
    #pragma unroll
    for (int i = 0; i < 4; i++)
        #pragma unroll
        for (int j = 0; j < 4; j++) acc[i][j] = zz;

    for (int k0 = 0; k0 < K; k0 += 64) {
        gload16(ga0 + k0,      &As[0][t8]);
        gload16(ga1 + k0,      &As[0][t8 + 2048]);
        gload16(ga0 + k0 + 32, &As[1][t8]);
        gload16(ga1 + k0 + 32, &As[1][t8 + 2048]);
        gload16(gw0 + k0,      &Ws[0][t8]);
        gload16(gw1 + k0,      &Ws[0][t8 + 2048]);
        gload16(gw0 + k0 + 32, &Ws[1][t8]);
        gload16(gw1 + k0 + 32, &Ws[1][t8 + 2048]);
        __syncthreads();
        short8 af[2][4], wf[2][4];
        #pragma unroll
        for (int kk = 0; kk < 2; kk++) {
            #pragma unroll
            for (int i = 0; i < 4; i++) af[kk][i] = *(const short8*)&As[kk][(mh + i * 16 + lr) * 32 + lk];
            #pragma unroll
            for (int j = 0; j < 4; j++) wf[kk][j] = *(const short8*)&Ws[kk][(nh + j * 16 + lr) * 32 + lk];
        }
        #pragma unroll
        for (int kk = 0; kk < 2; kk++)
            #pragma unroll
            for (int i = 0; i < 4; i++)
                #pragma unroll
                for (int j = 0; j < 4; j++)
                    acc[i][j] = __builtin_amdgcn_mfma_f32_16x16x32_bf16(af[kk][i], wf[kk][j], acc[i][j], 0, 0, 0);
        __syncthreads();
    }

    #pragma unroll
    for (int nt = 0; nt < 4; nt++) {
        int colbase = n0 + nh + nt * 16;       // 16-aligned; regions 256-aligned
        int col = colbase + lr;
        float bv = bias[col];
        if (QSC && colbase < 256) bv *= (float)QSCL;
        int region = QKV ? (colbase >> 8) : 0; // wave-uniform
        #pragma unroll
        for (int mt = 0; mt < 4; mt++) {
            int rowb = m0 + mh + mt * 16 + quad * 4;
            if (!QKV || region == 0) {
                #pragma unroll
                for (int r = 0; r < 4; r++) {
                    size_t cidx = (size_t)(rowb + r) * N + col;
                    float v = acc[mt][nt][r] + bv;
                    if (RELU) v = fmaxf(v, 0.f);
                    Cout[cidx] = f2b(v);
                }
            } else if (region == 1) {          // K -> Kb[b,h,s,32]
                int hh = (col >> 5) & 7, d = col & 31;
                int bb = rowb >> 9, s = rowb & 511;
                size_t kbase = ((size_t)(bb * 8 + hh) * 512 + s) * 32 + d;
                #pragma unroll
                for (int r = 0; r < 4; r++)
                    Kb[kbase + (size_t)r * 32] = f2b(acc[mt][nt][r] + bv);
            } else {                           // V -> Vt[bh][s/16][d][16] tiled
                int hh = (col >> 5) & 7, d = col & 31;
                int bb = rowb >> 9, s = rowb & 511;
                ushort4 w;
                w.x = f2b(acc[mt][nt][0] + bv);
                w.y = f2b(acc[mt][nt][1] + bv);
                w.z = f2b(acc[mt][nt][2] + bv);
                w.w = f2b(acc[mt][nt][3] + bv);
                size_t vidx = (((size_t)(bb * 8 + hh) * 32 + (s >> 4)) * 32 + d) * 16 + (s & 15);
                *(ushort4*)&Vt[vidx] = w;
            }
        }
    }
}

// ---------------------------------------------------------------------------
// Fused residual GEMM + LayerNorm, BK=64 via two k-half planes.
// Block = 64 rows x 256 cols; grid 512, (256,2).
template<int K>
__global__ __launch_bounds__(256, 2) void gemm_ln(const ushort* __restrict__ A,
                                                  const ushort* __restrict__ W,
                                                  const float* __restrict__ bias,
                                                  float* __restrict__ X,
                                                  const float* __restrict__ lng,
                                                  const float* __restrict__ lnb,
                                                  ushort* __restrict__ Hout)
{
    __shared__ ushort As[2][2048];      //  8 KB  [khalf][64 x 32]
    __shared__ ushort Ws[2][8192];      // 32 KB  [khalf][256 x 32]
    __shared__ float lds_s[64][4];      //  1 KB
    __shared__ float lds_q[64][4];      //  1 KB
    int t = threadIdx.x;
    int wave = t >> 6, lane = t & 63;
    int lr = lane & 15, quad = lane >> 4;
    int lk = quad * 8;
    int blk = blockIdx.x;               // grid 512
    int xcd = blk & 7;
    int m0 = (xcd * 64 + (blk >> 3)) * 64;
    int nh = wave * 64;

    const ushort* ga = A + (size_t)(m0 + (t >> 2)) * K + (t & 3) * 8;
    const ushort* gw = W + (size_t)(t >> 2) * K + (t & 3) * 8;
    int t8 = t * 8;

    f32x4 acc[4][4];
    f32x4 zz = {0.f, 0.f, 0.f, 0.f};
    #pragma unroll
    for (int i = 0; i < 4; i++)
        #pragma unroll
        for (int j = 0; j < 4; j++) acc[i][j] = zz;

    for (int k0 = 0; k0 < K; k0 += 64) {
        gload16(ga + k0,      &As[0][t8]);
        gload16(ga + k0 + 32, &As[1][t8]);
        #pragma unroll
        for (int j = 0; j < 4; j++) {
            gload16(gw + (size_t)(j * 64) * K + k0,      &Ws[0][t8 + j * 2048]);
            gload16(gw + (size_t)(j * 64) * K + k0 + 32, &Ws[1][t8 + j * 2048]);
        }
        __syncthreads();
        short8 af[2][4], wf[2][4];
        #pragma unroll
        for (int kk = 0; kk < 2; kk++) {
            #pragma unroll
            for (int i = 0; i < 4; i++) af[kk][i] = *(const short8*)&As[kk][(i * 16 + lr) * 32 + lk];
            #pragma unroll
            for (int j = 0; j < 4; j++) wf[kk][j] = *(const short8*)&Ws[kk][(nh + j * 16 + lr) * 32 + lk];
        }
        #pragma unroll
        for (int kk = 0; kk < 2; kk++)
            #pragma unroll
            for (int i = 0; i < 4; i++)
                #pragma unroll
                for (int j = 0; j < 4; j++)
                    acc[i][j] = __builtin_amdgcn_mfma_f32_16x16x32_bf16(af[kk][i], wf[kk][j], acc[i][j], 0, 0, 0);
        __syncthreads();
    }

    // epilogue pass 1: v = acc + bias + X; store X; keep v in acc; row partials
    float gc[4], bc[4], bi[4];
    #pragma unroll
    for (int nt = 0; nt < 4; nt++) {
        int col = nh + nt * 16 + lr;
        gc[nt] = lng[col]; bc[nt] = lnb[col]; bi[nt] = bias[col];
    }
    float psum[16], psq[16];
    #pragma unroll
    for (int e = 0; e < 16; e++) { psum[e] = 0.f; psq[e] = 0.f; }
    #pragma unroll
    for (int nt = 0; nt < 4; nt++) {
        #pragma unroll
        for (int mt = 0; mt < 4; mt++) {
            #pragma unroll
            for (int r = 0; r < 4; r++) {
                int row = m0 + mt * 16 + quad * 4 + r;
                size_t idx = (size_t)row * D_ + nh + nt * 16 + lr;
                float v = acc[mt][nt][r] + bi[nt] + X[idx];
                X[idx] = v;
                acc[mt][nt][r] = v;
                psum[mt * 4 + r] += v;
                psq[mt * 4 + r]  += v * v;
            }
        }
    }
    // reduce over lr (16 lanes per quad hold disjoint cols of same rows)
    #pragma unroll
    for (int e = 0; e < 16; e++) {
        float s = psum[e], q = psq[e];
        s += __shfl_xor(s, 1); q += __shfl_xor(q, 1);
        s += __shfl_xor(s, 2); q += __shfl_xor(q, 2);
        s += __shfl_xor(s, 4); q += __shfl_xor(q, 4);
        s += __shfl_xor(s, 8); q += __shfl_xor(q, 8);
        psum[e] = s; psq[e] = q;
    }
    if (lr == 0) {
        #pragma unroll
        for (int mt = 0; mt < 4; mt++)
            #pragma unroll
            for (int r = 0; r < 4; r++) {
                int rl = mt * 16 + quad * 4 + r;
                lds_s[rl][wave] = psum[mt * 4 + r];
                lds_q[rl][wave] = psq[mt * 4 + r];
            }
    }
    __syncthreads();
    // epilogue pass 2: finalize stats, write h
    #pragma unroll
    for (int mt = 0; mt < 4; mt++) {
        #pragma unroll
        for (int r = 0; r < 4; r++) {
            int rl = mt * 16 + quad * 4 + r;
            f32x4 ss = *(const f32x4*)lds_s[rl];
            f32x4 qq = *(const f32x4*)lds_q[rl];
            float s = ss[0] + ss[1] + ss[2] + ss[3];
            float q = qq[0] + qq[1] + qq[2] + qq[3];
            float mean = s * (1.f / 256.f);
            float rstd = rsqrtf(q * (1.f / 256.f) - mean * mean + 1e-5f);
            int row = m0 + mt * 16 + quad * 4 + r;
            #pragma unroll
            for (int nt = 0; nt < 4; nt++) {
                size_t idx = (size_t)row * D_ + nh + nt * 16 + lr;
                float hv = (acc[mt][nt][r] - mean) * rstd * gc[nt] + bc[nt];
                Hout[idx] = f2b(hv);
            }
        }
    }
}

// ---------------------------------------------------------------------------
// Flash attention, barrier-free (R7 proven config): no LDS, E in registers,
// PV on K=32 MFMA, full-stream prefetch + linear pointers, (256,4).
// Used for layers 0..2 only (layer 3 needs just the s=0 queries -> attn_last).
__global__ __launch_bounds__(256, 4) void attn_mfma(const ushort* __restrict__ qkv,
                                                    const ushort* __restrict__ Kb,
                                                    const ushort* __restrict__ Vt,
                                                    const unsigned char* __restrict__ et8,
                                                    const float* __restrict__ eemb,
                                                    ushort* __restrict__ o)
{
    int t = threadIdx.x;
    int wave = t >> 6, lane = t & 63;
    int lr = lane & 15, quad = lane >> 4;
    int lk = quad * 8;
    int blk = blockIdx.x;                    // grid 2048
    int b = ((blk >> 8) << 3) | (blk & 7);   // same-b blocks -> same XCD
    int h = (blk >> 3) & 7;
    int qq = (blk >> 6) & 3;
    int bh = b * 8 + h;
    int q0 = qq * 128 + wave * 32;
    // additive bias table (log2 domain): exp2(s + b*L2E)
    float eb0 = eemb[h] * L2E, eb1 = eemb[8 + h] * L2E, eb2 = eemb[16 + h] * L2E;
    uint tlo = (uint)f2b(eb0) | ((uint)f2b(eb1) << 16);
    uint thi = (uint)f2b(eb2);               // high half = bf16 0.0 for e==3

    short8 qf[2];
    #pragma unroll
    for (int X = 0; X < 2; X++)
        qf[X] = *(const short8*)(qkv + ((size_t)(b * S_ + q0 + X * 16 + lr)) * 768 + h * 32 + lk);
    // permuted K pointer: A row m=lr holds K seq g(lr) = (lr>>2)*8 + (lr&3)
    int gl = ((lr >> 2) << 3) | (lr & 3);
    const ushort* Kp = Kb + ((size_t)(bh * S_) + gl) * 32 + lk;
    // V B-fragment (16x16x32): lane needs V[k0+quad*8+j][d=lr], j=0..7
    //  = Vt tile (k0>>4)+(quad>>1), d=lr, sl=(quad&1)*8 + j  (16B contiguous)
    const ushort* Vp = Vt + (size_t)bh * 16384 + (quad >> 1) * 512 + lr * 16 + (quad & 1) * 8;
    // E per lane per X: 8 contiguous bytes at row (q0+X*16+lr), col k0+quad*8
    const unsigned char* Ep0 = et8 + ((size_t)(b * S_ + q0 + lr)) * 512 + quad * 8;
    const unsigned char* Ep1 = Ep0 + (size_t)16 * 512;

    const short8 vones8 = { (short)0x3F80, (short)0x3F80, (short)0x3F80, (short)0x3F80,
                            (short)0x3F80, (short)0x3F80, (short)0x3F80, (short)0x3F80 };

    f32x4 zz = {0.f, 0.f, 0.f, 0.f};
    f32x4 oacc[2][2], lacc[2];
    #pragma unroll
    for (int X = 0; X < 2; X++) { oacc[X][0] = zz; oacc[X][1] = zz; lacc[X] = zz; }

    // prefetch iter 0 (all three streams)
    short8 kf0 = *(const short8*)(Kp);
    short8 kf1 = *(const short8*)(Kp + 128);          // +4 seq rows
    uint2 e0 = *(const uint2*)(Ep0);
    uint2 e1 = *(const uint2*)(Ep1);
    short8 vb0 = *(const short8*)(Vp);
    short8 vb1 = *(const short8*)(Vp + 256);
    Kp += 1024; Ep0 += 32; Ep1 += 32; Vp += 1024;     // advance to iter 1

    #pragma unroll 2
    for (int it = 0; it < 16; ++it) {
        // prefetch next iteration (last-iter read is harmless in-workspace)
        short8 nk0 = *(const short8*)(Kp);
        short8 nk1 = *(const short8*)(Kp + 128);
        uint2 ne0 = *(const uint2*)(Ep0);
        uint2 ne1 = *(const uint2*)(Ep1);
        short8 nv0 = *(const short8*)(Vp);
        short8 nv1 = *(const short8*)(Vp + 256);
        Kp += 1024; Ep0 += 32; Ep1 += 32; Vp += 1024;
        #pragma unroll
        for (int X = 0; X < 2; X++) {
            uint Ea = X ? e1.x : e0.x;
            uint Eb = X ? e1.y : e0.y;
            // bias in C layout: c0[r] = bias[q=lr][k=k0+quad*8+r]; c1: +4
            f32x4 c0 = bsel4v(Ea, tlo, thi);
            f32x4 c1 = bsel4v(Eb, tlo, thi);
            // S^T: s0[r] = S[k=k0+quad*8+r][q=lr] (+bias); s1: +4
            f32x4 s0 = __builtin_amdgcn_mfma_f32_16x16x32_bf16(kf0, qf[X], c0, 0, 0, 0);
            f32x4 s1 = __builtin_amdgcn_mfma_f32_16x16x32_bf16(kf1, qf[X], c1, 0, 0, 0);
            float p0[4], p1[4];
            #pragma unroll
            for (int r = 0; r < 4; r++) {
                p0[r] = EXP2(s0[r]);
                p1[r] = EXP2(s1[r]);
            }
            // PA = native 16x16x32 A-fragment: lane holds P[q=lr][k=quad*8+j]
            union { short8 v; uint u[4]; } PA;
            PA.u[0] = pk_bf16(p0[0], p0[1]); PA.u[1] = pk_bf16(p0[2], p0[3]);
            PA.u[2] = pk_bf16(p1[0], p1[1]); PA.u[3] = pk_bf16(p1[2], p1[3]);
            oacc[X][0] = __builtin_amdgcn_mfma_f32_16x16x32_bf16(PA.v, vb0, oacc[X][0], 0, 0, 0);
            oacc[X][1] = __builtin_amdgcn_mfma_f32_16x16x32_bf16(PA.v, vb1, oacc[X][1], 0, 0, 0);
            lacc[X]    = __builtin_amdgcn_mfma_f32_16x16x32_bf16(PA.v, vones8, lacc[X], 0, 0, 0);
        }
        kf0 = nk0; kf1 = nk1; e0 = ne0; e1 = ne1; vb0 = nv0; vb1 = nv1;
    }

    // lacc[X][r] = full row-sum for q=quad*4+r, replicated across lr lanes
    #pragma unroll
    for (int X = 0; X < 2; X++) {
        #pragma unroll
        for (int r = 0; r < 4; r++) {
            int q = quad * 4 + r;                 // O rows: q, cols d = lr
            float inv = 1.f / lacc[X][r];
            size_t base = (size_t)(b * S_ + q0 + X * 16 + q) * D_ + h * 32;
            o[base + lr]      = f2b(oacc[X][0][r] * inv);
            o[base + 16 + lr] = f2b(oacc[X][1][r] * inv);
        }
    }
}

// ---------------------------------------------------------------------------
// Last-layer attention: only the game-token query (s=0) survives to the head.
// One wave per (b,h). Bias row at q=0 is all-zero (pad), so no et8 needed.
// Numerics match the MFMA path: bf16 inputs, fp32 acc, P rounded to bf16,
// denominator = sum of bf16 P.
__global__ __launch_bounds__(64) void attn_last(const ushort* __restrict__ qkv,
                                                const ushort* __restrict__ Kb,
                                                const ushort* __restrict__ Vt,
                                                ushort* __restrict__ o)
{
    int lane = threadIdx.x;
    int bh = blockIdx.x;                     // b*8 + h
    int b = bh >> 3, h = bh & 7;
    __shared__ float ps[512];

    // q row (pre-scaled by QSCL incl. log2e): qkv[(b*S)*768 + h*32 + d]
    const ushort* qp = qkv + (size_t)(b * S_) * 768 + h * 32;
    float q[32];
    #pragma unroll
    for (int d8 = 0; d8 < 4; d8++) {
        short8 v = *(const short8*)(qp + d8 * 8);
        #pragma unroll
        for (int j = 0; j < 8; j++) q[d8 * 8 + j] = b2f((ushort)v[j]);
    }
    // scores for 8 keys per lane; K[k][d] = Kb[(bh*512 + k)*32 + d]
    const ushort* kp = Kb + ((size_t)bh * 512 + lane * 8) * 32;
    float lsum = 0.f;
    #pragma unroll
    for (int j = 0; j < 8; j++) {
        float s = 0.f;
        #pragma unroll
        for (int d8 = 0; d8 < 4; d8++) {
            short8 kv = *(const short8*)(kp + j * 32 + d8 * 8);
            #pragma unroll
            for (int e = 0; e < 8; e++) s += q[d8 * 8 + e] * b2f((ushort)kv[e]);
        }
        float pe = b2f(f2b(EXP2(s)));        // bias 0; round P to bf16
        ps[lane * 8 + j] = pe;
        lsum += pe;
    }
    #pragma unroll
    for (int off = 32; off >= 1; off >>= 1) lsum += __shfl_xor(lsum, off);
    __syncthreads();

    // PV: lane = kh*32 + d; each half-wave covers 256 keys for its d
    int d = lane & 31, kh = lane >> 5;
    const ushort* vp = Vt + (size_t)bh * 16384 + d * 16;   // V[k][d] at +(k>>4)*512+(k&15)
    float acc = 0.f;
    for (int k = kh * 256; k < kh * 256 + 256; k += 16) {
        const ushort* vt = vp + (size_t)(k >> 4) * 512;
        #pragma unroll
        for (int e = 0; e < 16; e++) acc += ps[k + e] * b2f(vt[e]);
    }
    acc += __shfl_xor(acc, 32);
    if (lane < 32)
        o[(size_t)(b * S_) * D_ + h * 32 + d] = f2b(acc / lsum);
}

// ---------------------------------------------------------------------------
// Last-layer tail for one game-token row per block:
// xmid = ob@outW^T + out_b + x ; h2 = LN2(xmid) ; f = relu(h2@ff1W^T + b1) ;
// x_final = f@ff2W^T + b2 + xmid   (only these 64 rows feed the head).
// Same bf16-input/fp32-acc numerics as the GEMM path (h2, f rounded to bf16).
__global__ __launch_bounds__(256) void last_tail(const ushort* __restrict__ ob,
                                                 const ushort* __restrict__ outw,
                                                 const float* __restrict__ outb,
                                                 const float* __restrict__ ln2g,
                                                 const float* __restrict__ ln2b,
                                                 const ushort* __restrict__ ff1w,
                                                 const float* __restrict__ ff1b,
                                                 const ushort* __restrict__ ff2w,
                                                 const float* __restrict__ ff2b,
                                                 float* __restrict__ X)
{
    __shared__ float obs[256];
    __shared__ ushort h2s[256];
    __shared__ ushort ffs[512];
    __shared__ float red[8];
    int t = threadIdx.x;
    int b = blockIdx.x;
    size_t row = (size_t)b * S_;              // s = 0

    obs[t] = b2f(ob[row * D_ + t]);
    __syncthreads();

    // out-proj col t
    const ushort* w0 = outw + (size_t)t * 256;
    float acc = 0.f;
    for (int k8 = 0; k8 < 256; k8 += 8) {
        short8 wv = *(const short8*)(w0 + k8);
        #pragma unroll
        for (int e = 0; e < 8; e++) acc += obs[k8 + e] * b2f((ushort)wv[e]);
    }
    float xv = acc + outb[t] + X[row * D_ + t];

    // LN2 over the 256 xv values
    float s1 = xv, s2 = xv * xv;
    #pragma unroll
    for (int off = 32; off >= 1; off >>= 1) { s1 += __shfl_xor(s1, off); s2 += __shfl_xor(s2, off); }
    int wv_ = t >> 6, lane = t & 63;
    if (lane == 0) { red[wv_] = s1; red[4 + wv_] = s2; }
    __syncthreads();
    float S1 = red[0] + red[1] + red[2] + red[3];
    float S2 = red[4] + red[5] + red[6] + red[7];
    float mean = S1 * (1.f / 256.f);
    float rstd = rsqrtf(S2 * (1.f / 256.f) - mean * mean + 1e-5f);
    h2s[t] = f2b((xv - mean) * rstd * ln2g[t] + ln2b[t]);
    __syncthreads();

    // ff1: cols t and t+256
    #pragma unroll
    for (int cc = 0; cc < 2; cc++) {
        int col = t + cc * 256;
        const ushort* w1 = ff1w + (size_t)col * 256;
        float a = 0.f;
        for (int k8 = 0; k8 < 256; k8 += 8) {
            short8 wv1 = *(const short8*)(w1 + k8);
            #pragma unroll
            for (int e = 0; e < 8; e++) a += b2f(h2s[k8 + e]) * b2f((ushort)wv1[e]);
        }
        ffs[col] = f2b(fmaxf(a + ff1b[col], 0.f));
    }
    __syncthreads();

    // ff2 col t + residual
    const ushort* w2 = ff2w + (size_t)t * 512;
    float a2 = 0.f;
    for (int k8 = 0; k8 < 512; k8 += 8) {
        short8 wv2 = *(const short8*)(w2 + k8);
        #pragma unroll
        for (int e = 0; e < 8; e++) a2 += b2f(ffs[k8 + e]) * b2f((ushort)wv2[e]);
    }
    X[row * D_ + t] = a2 + ff2b[t] + xv;
}

// ---------------------------------------------------------------------------
// Head (fp32)
__global__ __launch_bounds__(64) void head_kernel(const float* __restrict__ x,
                                                  const float* __restrict__ fc1w,
                                                  const float* __restrict__ fc1b,
                                                  const float* __restrict__ polw,
                                                  const float* __restrict__ polb,
                                                  const float* __restrict__ valw,
                                                  const float* __restrict__ valb,
                                                  float* __restrict__ out)
{
    __shared__ float o1[64];
    int b = blockIdx.x;
    int t = threadIdx.x;
    const float* g = x + (size_t)b * S_ * D_;
    float acc = fc1b[t];
    for (int k = 0; k < D_; k++) acc += g[k] * fc1w[t * D_ + k];
    o1[t] = fmaxf(acc, 0.f);
    __syncthreads();
    if (t < BW_) {
        float a = polb[t];
        for (int k = 0; k < 64; k++) a += o1[k] * polw[t * 64 + k];
        out[b * BW_ + t] = a;
    } else if (t == BW_) {
        float a = valb[0];
        for (int k = 0; k < 64; k++) a += o1[k] * valw[k];
        out[B_ * BW_ + b] = tanhf(a);
    }
}

// ---------------------------------------------------------------------------
extern "C" void kernel_launch(void* const* d_in, const int* in_sizes, int n_in,
                              void* d_out, int out_size, void* d_ws, size_t ws_size,
                              hipStream_t stream)
{
    const int*   cs    = (const int*)d_in[0];
    const int*   etm   = (const int*)d_in[1];
    const float* patch = (const float*)d_in[2];
    const float* game  = (const float*)d_in[3];
    const float* eemb  = (const float*)d_in[4];
    const float* in_w  = (const float*)d_in[5];
    const float* in_b  = (const float*)d_in[6];
    const float* out_w = (const float*)d_in[7];
    const float* out_b = (const float*)d_in[8];
    const float* ff1_w = (const float*)d_in[9];
    const float* ff1_b = (const float*)d_in[10];
    const float* ff2_w = (const float*)d_in[11];
    const float* ff2_b = (const float*)d_in[12];
    const float* ln1_g = (const float*)d_in[13];
    const float* ln1_b = (const float*)d_in[14];
    const float* ln2_g = (const float*)d_in[15];
    const float* ln2_b = (const float*)d_in[16];
    const float* fc1_w = (const float*)d_in[17];
    const float* fc1_b = (const float*)d_in[18];
    const float* pol_w = (const float*)d_in[19];
    const float* pol_b = (const float*)d_in[20];
    const float* val_w = (const float*)d_in[21];
    const float* val_b = (const float*)d_in[22];
    float* out = (float*)d_out;

    char* base = (char*)d_ws;
    float*  x     = (float*)(base + 0);                    // 33554432 B
    ushort* h     = (ushort*)(base + 33554432);            // 16777216 B
    ushort* qkvb  = (ushort*)(base + 50331648);            // 50331648 B (also FF buf)
    ushort* Kb    = (ushort*)(base + 100663296);           // 16777216 B
    ushort* Vt    = (ushort*)(base + 117440512);           // 16777216 B
    ushort* ob    = (ushort*)(base + 134217728);           // 16777216 B
    unsigned char* et8 = (unsigned char*)(base + 150994944); // 16777216 B
    ushort* inwb  = (ushort*)(base + 167772160);           //  1572864 B
    ushort* outwb = (ushort*)(base + 169345024);           //   524288 B
    ushort* ff1wb = (ushort*)(base + 169869312);           //  1048576 B
    ushort* ff2wb = (ushort*)(base + 170917888);           //  1048576 B

    build_et8<<<65536, 256, 0, stream>>>(etm, et8);
    convert_all<<<2048, 256, 0, stream>>>(in_w, out_w, ff1_w, ff2_w,
                                          inwb, outwb, ff1wb, ff2wb);
    // fused build_x + initial LN1 (layer 0); later LNs fused into gemm_ln
    build_ln<<<8192, 256, 0, stream>>>(cs, patch, game, ln1_g, ln1_b, x, h);

    for (int i = 0; i < L_; i++) {
        // qkv GEMM with fused K/V repack (Q -> qkvb, K -> Kb, V^T tiled -> Vt)
        gemm_lds<256, 6, false, true, true><<<1536, 256, 0, stream>>>(
            h, inwb + (size_t)i * 196608, in_b + i * 768, qkvb, Kb, Vt);
        if (i < L_ - 1) {
            attn_mfma<<<2048, 256, 0, stream>>>(qkvb, Kb, Vt, et8, eemb, ob);
            // out-proj + residual + LN2 -> x (fp32), h (bf16)
            gemm_ln<256><<<512, 256, 0, stream>>>(
                ob, outwb + (size_t)i * 65536, out_b + i * 256, x,
                ln2_g + i * D_, ln2_b + i * D_, h);
            gemm_lds<256, 4, true, false, false><<<1024, 256, 0, stream>>>(
                h, ff1wb + (size_t)i * 131072, ff1_b + i * 512, qkvb, nullptr, nullptr);
            // ff2 + residual + LN1(next layer) -> x (fp32), h (bf16)
            gemm_ln<512><<<512, 256, 0, stream>>>(
                qkvb, ff2wb + (size_t)i * 131072, ff2_b + i * 256, x,
                ln1_g + (i + 1) * D_, ln1_b + (i + 1) * D_, h);
        } else {
            // Last layer: only the s=0 rows reach the head.
            attn_last<<<512, 64, 0, stream>>>(qkvb, Kb, Vt, ob);
            last_tail<<<64, 256, 0, stream>>>(
                ob, outwb + (size_t)i * 65536, out_b + i * 256,
                ln2_g + i * D_, ln2_b + i * D_,
                ff1wb + (size_t)i * 131072, ff1_b + i * 512,
                ff2wb + (size_t)i * 131072, ff2_b + i * 256, x);
        }
    }
    head_kernel<<<B_, 64, 0, stream>>>(x, fc1_w, fc1_b, pol_w, pol_b, val_w, val_b, out);
}